// Round 7
// baseline (241.746 us; speedup 1.0000x reference)
//
#include <hip/hip_runtime.h>
#include <hip/hip_bf16.h>

typedef __attribute__((ext_vector_type(8))) short bf16x8;
typedef __attribute__((ext_vector_type(4))) float f32x4;

#define MFMA16(A, B, C) __builtin_amdgcn_mfma_f32_16x16x32_bf16(A, B, C, 0, 0, 0)

__device__ __forceinline__ unsigned short f2bf(float f) {
    unsigned int u = __float_as_uint(f);
    u += 0x7fffu + ((u >> 16) & 1u);
    return (unsigned short)(u >> 16);
}
__device__ __forceinline__ float bf2f(unsigned short h) {
    return __uint_as_float(((unsigned int)h) << 16);
}
__device__ __forceinline__ unsigned int pack_bf2(float lo, float hi) {
    __hip_bfloat162 h = __float22bfloat162_rn(make_float2(lo, hi)); // v_cvt_pk_bf16_f32
    return *reinterpret_cast<unsigned int*>(&h);
}

__device__ __forceinline__ void gload_lds16(const void* g, void* l) {
    __builtin_amdgcn_global_load_lds(
        (__attribute__((address_space(1))) unsigned int*)g,
        (__attribute__((address_space(3))) unsigned int*)l, 16, 0, 0);
}

// LDS swizzle for [128 rows][64 bf16] regions (128 B/row): XOR chunk with row&7.
__device__ __forceinline__ int swz128(int by) {
    return by ^ (((by >> 7) & 7) << 4);
}

// ---------------------------------------------------------------- converts
__global__ void cvt_kernel(const float* __restrict__ in, unsigned short* __restrict__ out, int n4) {
    const int i = blockIdx.x * 256 + threadIdx.x;
    if (i >= n4) return;
    const float4 v = ((const float4*)in)[i];
    uint2 o;
    o.x = pack_bf2(v.x, v.y);
    o.y = pack_bf2(v.z, v.w);
    ((uint2*)out)[i] = o;
}

// ---------------------------------------------------------------- doc starts
__global__ void docstart_kernel(const int* __restrict__ sid, int* __restrict__ ds) {
    const int i = blockIdx.x * 256 + threadIdx.x; // 0..4095
    const int b = i >> 11, s = i & 2047;
    const int* row = sid + b * 2048;
    const int v = row[s];
    int lo = 0, hi = s;
    while (lo < hi) { const int mid = (lo + hi) >> 1; if (row[mid] < v) lo = mid + 1; else hi = mid; }
    ds[i] = lo;
}

// ---------------------------------------------------------------- QKV 256x256 GEMM, 2-phase/K-tile
// with cross-phase ds_read prefetch (counted lgkmcnt) to overlap LDS pipe with MFMA pipe.
// Phase A: MFMA mh=0 (A0 prefetched last phase; B read+waited here; A1 reads in flight).
// Phase B: MFMA mh=1 (A1 waited; next group's A0 reads in flight). 2 barriers/K-tile.
// Staging: PH_A stages {B1,A1}[g+1]; PH_B stages {A0,B0}[g+2].
// vmcnt ledger: PH_A entry vmcnt(4) retires {B1,A1}[g]; PH_B vmcnt(8) (after its stages)
// retires {A0,B0}[g+1] before the A0 prefetch read. Tails: vmcnt(0)@PH_A(NT-1), vmcnt(4)@PH_B(NT-2).
#define QKV_K 2048
#define QKV_NT 32

#define DSR(dst, addr, IMM) \
    asm volatile("ds_read_b128 %0, %1 offset:" #IMM : "=v"(dst) : "v"(addr))
#define VMW(N) asm volatile("s_waitcnt vmcnt(" #N ")" ::: "memory")
#define LGW(N) do { asm volatile("s_waitcnt lgkmcnt(" #N ")" ::: "memory"); \
                    __builtin_amdgcn_sched_barrier(0); } while (0)
#define BAR() __builtin_amdgcn_s_barrier()

#define READ_B8(bb0, bb1) do { \
    DSR(Br[0][0][0], bb0, 0);     DSR(Br[0][0][1], bb1, 0); \
    DSR(Br[0][1][0], bb0, 2048);  DSR(Br[0][1][1], bb1, 2048); \
    DSR(Br[1][0][0], bb0, 16384); DSR(Br[1][0][1], bb1, 16384); \
    DSR(Br[1][1][0], bb0, 18432); DSR(Br[1][1][1], bb1, 18432); \
} while (0)

#define READ_A8_H0(Ar, ab0, ab1) do { \
    DSR(Ar[0][0], ab0, 0);     DSR(Ar[0][1], ab1, 0); \
    DSR(Ar[1][0], ab0, 2048);  DSR(Ar[1][1], ab1, 2048); \
    DSR(Ar[2][0], ab0, 4096);  DSR(Ar[2][1], ab1, 4096); \
    DSR(Ar[3][0], ab0, 6144);  DSR(Ar[3][1], ab1, 6144); \
} while (0)

#define READ_A8_H1(Ar, ab0, ab1) do { \
    DSR(Ar[0][0], ab0, 16384); DSR(Ar[0][1], ab1, 16384); \
    DSR(Ar[1][0], ab0, 18432); DSR(Ar[1][1], ab1, 18432); \
    DSR(Ar[2][0], ab0, 20480); DSR(Ar[2][1], ab1, 20480); \
    DSR(Ar[3][0], ab0, 22528); DSR(Ar[3][1], ab1, 22528); \
} while (0)

__global__ __launch_bounds__(512, 2) void gemm_qkv8(
    const unsigned short* __restrict__ A,
    const unsigned short* __restrict__ B,
    unsigned short* __restrict__ oq,
    unsigned short* __restrict__ ok,
    unsigned short* __restrict__ ov)
{
    __shared__ __align__(16) unsigned short S[2][2][2][8192]; // [buf][op][half][16KB]
    const int tid = threadIdx.x, lane = tid & 63, w = tid >> 6;
    const int wr = w >> 2, wc = w & 3;
    const int lr = lane & 15, lc = lane >> 4;

    // XCD swizzle over 192 blocks (192 % 8 == 0)
    int bid = blockIdx.x;
    bid = (bid & 7) * 24 + (bid >> 3);
    const int m0 = (bid / 12) * 256, n0 = (bid % 12) * 256;

    // staging geometry: linear LDS dest, inverse-swizzled global source (rule #21)
    const int o0 = (w << 11) + (lane << 4);
    const int o1 = o0 + 1024;
    const int v0 = swz128(o0), v1 = swz128(o1);
    const int r0 = v0 >> 7, c0 = (v0 & 127) >> 1;
    const int r1 = v1 >> 7, c1 = (v1 & 127) >> 1;
    const size_t aoff0 = (size_t)(m0 + r0) * QKV_K + c0;
    const size_t aoff1 = (size_t)(m0 + r1) * QKV_K + c1;
    const size_t boff0 = (size_t)(n0 + r0) * QKV_K + c0;
    const size_t boff1 = (size_t)(n0 + r1) * QKV_K + c1;
    const int d0 = o0 >> 1, d1 = o1 >> 1;

    // ds_read bases: addr = base + h*16384 (A) / nh*16384 (B) + i*2048 (imm offsets)
    const unsigned sbase =
        (unsigned)(size_t)(__attribute__((address_space(3))) unsigned short*)&S[0][0][0][0];
    const int sw = (lr & 7) << 4;
    const int arow = (wr * 64 + lr) << 7;
    const int brow = (wc * 32 + lr) << 7;
    const int xk0 = (lc << 4) ^ sw;
    const int xk1 = (64 | (lc << 4)) ^ sw;

    f32x4 acc[2][2][4][2];
#pragma unroll
    for (int a = 0; a < 2; a++)
#pragma unroll
        for (int bq = 0; bq < 2; bq++)
#pragma unroll
            for (int i = 0; i < 4; i++)
#pragma unroll
                for (int j = 0; j < 2; j++) acc[a][bq][i][j] = (f32x4){0.f, 0.f, 0.f, 0.f};

    bf16x8 A0r[4][2], A1r[4][2], Br[2][2][2];

    auto STAGE_A = [&](int bf, int h, int kt) {
        gload_lds16(A + aoff0 + (size_t)h * 128 * QKV_K + (size_t)kt * 64, &S[bf][0][h][d0]);
        gload_lds16(A + aoff1 + (size_t)h * 128 * QKV_K + (size_t)kt * 64, &S[bf][0][h][d1]);
    };
    auto STAGE_B = [&](int bf, int h, int kt) {
        gload_lds16(B + boff0 + (size_t)h * 128 * QKV_K + (size_t)kt * 64, &S[bf][1][h][d0]);
        gload_lds16(B + boff1 + (size_t)h * 128 * QKV_K + (size_t)kt * 64, &S[bf][1][h][d1]);
    };
    auto MFMA_HALF = [&](f32x4 (&ac)[2][4][2], bf16x8 (&Ar)[4][2]) {
        __builtin_amdgcn_s_setprio(1);
#pragma unroll
        for (int nh = 0; nh < 2; nh++)
#pragma unroll
            for (int i = 0; i < 4; i++)
#pragma unroll
                for (int j = 0; j < 2; j++)
#pragma unroll
                    for (int kh = 0; kh < 2; kh++)
                        ac[nh][i][j] = MFMA16(Ar[i][kh], Br[nh][j][kh], ac[nh][i][j]);
        __builtin_amdgcn_s_setprio(0);
    };

    // ---- prologue: A0,B0[0]; B1,A1[0]; A0,B0[1]; retire tile-0's A0,B0; prefetch A0[0] reads
    STAGE_A(0, 0, 0); STAGE_B(0, 0, 0);
    STAGE_B(0, 1, 0); STAGE_A(0, 1, 0);
    STAGE_A(1, 0, 1); STAGE_B(1, 0, 1);
    VMW(8);
    {
        const unsigned ab0 = sbase + arow + xk0;
        const unsigned ab1 = sbase + arow + xk1;
        READ_A8_H0(A0r, ab0, ab1);
    }

#pragma unroll 1
    for (int g = 0; g < QKV_NT; ++g) {
        const int bf = g & 1;
        const unsigned ab0 = sbase + (bf << 16) + arow + xk0;
        const unsigned ab1 = sbase + (bf << 16) + arow + xk1;
        const unsigned bb0 = sbase + (bf << 16) + 32768 + brow + xk0;
        const unsigned bb1 = sbase + (bf << 16) + 32768 + brow + xk1;

        // ================= PH_A: compute mh=0 =================
        BAR();
        if (g == QKV_NT - 1) { VMW(0); } else { VMW(4); } // retire {B1,A1}[g]
        if (g + 1 < QKV_NT) { STAGE_B(bf ^ 1, 1, g + 1); STAGE_A(bf ^ 1, 1, g + 1); }
        READ_B8(bb0, bb1);        // B[g], waited this phase
        READ_A8_H1(A1r, ab0, ab1); // A1[g], stays in flight
        LGW(8);                   // A0[g] + B[g] complete; A1 flying
        MFMA_HALF(acc[0], A0r);

        // ================= PH_B: compute mh=1 =================
        BAR();
        if (g + 2 < QKV_NT) { STAGE_A(bf, 0, g + 2); STAGE_B(bf, 0, g + 2); }
        if (g + 1 < QKV_NT) {
            if (g == QKV_NT - 2) { VMW(4); } else { VMW(8); } // retire {A0,B0}[g+1]
            const unsigned nab0 = sbase + ((bf ^ 1) << 16) + arow + xk0;
            const unsigned nab1 = sbase + ((bf ^ 1) << 16) + arow + xk1;
            READ_A8_H0(A0r, nab0, nab1); // prefetch next group's A0
            LGW(8);                      // A1[g] complete; A0' flying
        } else {
            LGW(0);
        }
        MFMA_HALF(acc[1], A1r);
    }

    // ---- epilogue: scatter into Q:(B,32,S,64), K/V:(B,8,S,64) bf16
#pragma unroll
    for (int mh = 0; mh < 2; mh++)
#pragma unroll
        for (int nh = 0; nh < 2; nh++)
#pragma unroll
            for (int i = 0; i < 4; i++)
#pragma unroll
                for (int j = 0; j < 2; j++) {
                    const int n = n0 + nh * 128 + wc * 32 + j * 16 + lr;
                    const int d = n & 63;
                    const int hh6 = n >> 6;
#pragma unroll
                    for (int r = 0; r < 4; r++) {
                        const int m = m0 + mh * 128 + wr * 64 + i * 16 + lc * 4 + r;
                        const int bb = m >> 11, s = m & 2047;
                        const unsigned short val = f2bf(acc[mh][nh][i][j][r]);
                        if (n < 2048) {
                            oq[((((size_t)bb * 32 + hh6) * 2048 + s) << 6) + d] = val;
                        } else if (n < 2560) {
                            ok[((((size_t)bb * 8 + (hh6 - 32)) * 2048 + s) << 6) + d] = val;
                        } else {
                            ov[((((size_t)bb * 8 + (hh6 - 40)) * 2048 + s) << 6) + d] = val;
                        }
                    }
                }
}

// ---------------------------------------------------------------- bt-GEMM (m97 structure + XCD swizzle) for out-proj
template <int EPI>
__global__ __launch_bounds__(256) void gemm_bt(
    const unsigned short* __restrict__ A,
    const unsigned short* __restrict__ B,
    int K, int N,
    unsigned short* __restrict__ oq,
    unsigned short* __restrict__ ok,
    unsigned short* __restrict__ ov,
    float* __restrict__ of)
{
    __shared__ __align__(16) unsigned short sA[128 * 32];
    __shared__ __align__(16) unsigned short sB[128 * 32];
    const int tid = threadIdx.x;
    const int lane = tid & 63, wave = tid >> 6;
    const int wr = wave >> 1, wc = wave & 1;
    const int lr = lane & 15, lc = lane >> 4;

    int bid = blockIdx.y * gridDim.x + blockIdx.x;
    const int cpx = (gridDim.x * gridDim.y) >> 3;
    bid = (bid & 7) * cpx + (bid >> 3);
    const int m0 = (bid / gridDim.x) * 128, n0 = (bid % gridDim.x) * 128;

    f32x4 acc[4][4];
#pragma unroll
    for (int i = 0; i < 4; i++)
#pragma unroll
        for (int j = 0; j < 4; j++) acc[i][j] = (f32x4){0.f, 0.f, 0.f, 0.f};

    const int u0 = tid, u1 = tid + 256;
    for (int k0 = 0; k0 < K; k0 += 32) {
        __syncthreads();
        gload_lds16(A + (size_t)(m0 + (u0 >> 2)) * K + k0 + (u0 & 3) * 8, &sA[u0 * 8]);
        gload_lds16(A + (size_t)(m0 + (u1 >> 2)) * K + k0 + (u1 & 3) * 8, &sA[u1 * 8]);
        gload_lds16(B + (size_t)(n0 + (u0 >> 2)) * K + k0 + (u0 & 3) * 8, &sB[u0 * 8]);
        gload_lds16(B + (size_t)(n0 + (u1 >> 2)) * K + k0 + (u1 & 3) * 8, &sB[u1 * 8]);
        __syncthreads();
        bf16x8 af[4], bfv[4];
#pragma unroll
        for (int i = 0; i < 4; i++) {
            af[i]  = *(const bf16x8*)&sA[(wr * 64 + i * 16 + lr) * 32 + lc * 8];
            bfv[i] = *(const bf16x8*)&sB[(wc * 64 + i * 16 + lr) * 32 + lc * 8];
        }
#pragma unroll
        for (int i = 0; i < 4; i++)
#pragma unroll
            for (int j = 0; j < 4; j++) acc[i][j] = MFMA16(af[i], bfv[j], acc[i][j]);
    }

    if (EPI == 0) {
#pragma unroll
        for (int i = 0; i < 4; i++) {
#pragma unroll
            for (int j = 0; j < 4; j++) {
                const int n = n0 + wc * 64 + j * 16 + lr;
                const int d = n & 63;
#pragma unroll
                for (int r = 0; r < 4; r++) {
                    const int m = m0 + wr * 64 + i * 16 + lc * 4 + r;
                    const int bb = m >> 11, s = m & 2047;
                    const unsigned short val = f2bf(acc[i][j][r]);
                    if (n < 2048) {
                        const int hh = n >> 6;
                        oq[((((size_t)bb * 32 + hh) * 2048 + s) << 6) + d] = val;
                    } else if (n < 2560) {
                        const int hh = (n >> 6) - 32;
                        ok[((((size_t)bb * 8 + hh) * 2048 + s) << 6) + d] = val;
                    } else {
                        const int hh = (n >> 6) - 40;
                        ov[((((size_t)bb * 8 + hh) * 2048 + s) << 6) + d] = val;
                    }
                }
            }
        }
    } else {
#pragma unroll
        for (int i = 0; i < 4; i++)
#pragma unroll
            for (int j = 0; j < 4; j++)
#pragma unroll
                for (int r = 0; r < 4; r++) {
                    const int m = m0 + wr * 64 + i * 16 + lc * 4 + r;
                    const int n = n0 + wc * 64 + j * 16 + lr;
                    of[(size_t)m * N + n] = acc[i][j][r];
                }
    }
}

// ---------------------------------------------------------------- RoPE (in-place on Q and K, bf16)
__global__ void rope_kernel(unsigned short* __restrict__ Qb,
                            unsigned short* __restrict__ Kb,
                            const float* __restrict__ fc)
{
    const int NQ = 2 * 32 * 2048 * 32;
    int i = blockIdx.x * 256 + threadIdx.x;
    unsigned short* base;
    if (i < NQ) base = Qb;
    else { base = Kb; i -= NQ; }
    const int p = i & 31, s = (i >> 5) & 2047, bh = i >> 16;
    const size_t off = (((size_t)bh * 2048 + s) << 6) + p * 2;
    const unsigned int w = *(const unsigned int*)&base[off];
    const float t0 = bf2f((unsigned short)(w & 0xffffu));
    const float t1 = bf2f((unsigned short)(w >> 16));
    const float c = fc[(s * 32 + p) * 2], sn = fc[(s * 32 + p) * 2 + 1];
    *(unsigned int*)&base[off] = pack_bf2(t0 * c - t1 * sn, t0 * sn + t1 * c);
}

// ---------------------------------------------------------------- flash attention v3 (unchanged, verified)
__global__ __launch_bounds__(256) void attn_kernel(
    const unsigned short* __restrict__ Q,
    const unsigned short* __restrict__ K,
    const unsigned short* __restrict__ V,
    const int* __restrict__ dstart,
    unsigned short* __restrict__ AO)
{
    const int qt = 31 - blockIdx.x; // heavy blocks first
    const int h = blockIdx.y, b = blockIdx.z;
    const int kvh = h >> 2;
    const int tid = threadIdx.x, lane = tid & 63, wave = tid >> 6;
    const int lr = lane & 15, lc = lane >> 4;
    const int q0 = qt * 64;
    const int qw = q0 + wave * 16;

    __shared__ __align__(16) unsigned short sK[64 * 64];   // chunk-XOR swizzled
    __shared__ __align__(16) unsigned short sVt[64][72];   // V^T, conflict-free writes

    const unsigned short* Qh = Q + (((size_t)b * 32 + h) * 2048) * 64;
    const unsigned short* Kh = K + (((size_t)b * 8 + kvh) * 2048) * 64;
    const unsigned short* Vh = V + (((size_t)b * 8 + kvh) * 2048) * 64;

    const bf16x8 qf0 = *(const bf16x8*)&Qh[(size_t)(qw + lr) * 64 + lc * 8];
    const bf16x8 qf1 = *(const bf16x8*)&Qh[(size_t)(qw + lr) * 64 + 32 + lc * 8];

    const int qglob = qw + lr;
    const int dsl = dstart[b * 2048 + qglob];
    const int ds_wmin = dstart[b * 2048 + qw];
    const int t0 = dstart[b * 2048 + q0] & ~63;

    float mrow = -1e30f, lrow = 0.f;
    f32x4 oacc[4];
#pragma unroll
    for (int j = 0; j < 4; j++) oacc[j] = (f32x4){0.f, 0.f, 0.f, 0.f};

    for (int t = t0; t < q0 + 64; t += 64) {
        __syncthreads();
        {
            int slot = tid;
            int r = slot >> 3, c = slot & 7;
            gload_lds16(Kh + (size_t)(t + r) * 64 + ((c ^ (r & 7)) * 8), &sK[slot * 8]);
            slot = tid + 256; r = slot >> 3; c = slot & 7;
            gload_lds16(Kh + (size_t)(t + r) * 64 + ((c ^ (r & 7)) * 8), &sK[slot * 8]);
        }
        {
            const int w8 = wave * 8;
            const uint4 va = *(const uint4*)&Vh[(size_t)(t + lane) * 64 + w8];
            const uint4 vb = *(const uint4*)&Vh[(size_t)(t + lane) * 64 + 32 + w8];
            const unsigned short* pa = (const unsigned short*)&va;
            const unsigned short* pb = (const unsigned short*)&vb;
#pragma unroll
            for (int e = 0; e < 8; e++) sVt[w8 + e][lane] = pa[e];
#pragma unroll
            for (int e = 0; e < 8; e++) sVt[32 + w8 + e][lane] = pb[e];
        }
        asm volatile("s_waitcnt vmcnt(0)" ::: "memory");
        __syncthreads();
        if (t > qw + 15 || t + 63 < ds_wmin) continue;

        f32x4 sc[4];
#pragma unroll
        for (int kk = 0; kk < 4; kk++) {
            const int krow = kk * 16 + lr;
            const bf16x8 kf0 = *(const bf16x8*)&sK[krow * 64 + ((lc ^ (lr & 7)) * 8)];
            const bf16x8 kf1 = *(const bf16x8*)&sK[krow * 64 + (((4 + lc) ^ (lr & 7)) * 8)];
            f32x4 a = (f32x4){0.f, 0.f, 0.f, 0.f};
            a = MFMA16(kf0, qf0, a);
            a = MFMA16(kf1, qf1, a);
            sc[kk] = a;
        }
        float vmax = -3e38f;
#pragma unroll
        for (int kk = 0; kk < 4; kk++)
#pragma unroll
            for (int r = 0; r < 4; r++) {
                const int kpos = t + kk * 16 + lc * 4 + r;
                const bool okm = (kpos <= qglob) && (kpos >= dsl);
                sc[kk][r] = okm ? sc[kk][r] * 0.125f : -3e38f;
                vmax = fmaxf(vmax, sc[kk][r]);
            }
        vmax = fmaxf(vmax, __shfl_xor(vmax, 16));
        vmax = fmaxf(vmax, __shfl_xor(vmax, 32));
        const float mnew = fmaxf(mrow, vmax);
        const float corr = __expf(mrow - mnew);
        mrow = mnew;

        float rsum = 0.f;
        unsigned int pk[4][2];
#pragma unroll
        for (int kk = 0; kk < 4; kk++) {
            const float p0 = __expf(sc[kk][0] - mnew);
            const float p1 = __expf(sc[kk][1] - mnew);
            const float p2 = __expf(sc[kk][2] - mnew);
            const float p3 = __expf(sc[kk][3] - mnew);
            rsum += (p0 + p1) + (p2 + p3);
            pk[kk][0] = pack_bf2(p0, p1);
            pk[kk][1] = pack_bf2(p2, p3);
        }
        rsum += __shfl_xor(rsum, 16);
        rsum += __shfl_xor(rsum, 32);
        lrow = lrow * corr + rsum;
#pragma unroll
        for (int j = 0; j < 4; j++)
#pragma unroll
            for (int r = 0; r < 4; r++) oacc[j][r] *= corr;

        const int srcEven = 32 * (lc & 1) + lr;
        const int srcOdd  = srcEven + 16;
        const bool hiKK = (lc & 2) != 0;
        union { unsigned int w[4]; bf16x8 v; } B0, B1;
        {
            unsigned int a, c;
            a = __shfl(pk[0][0], srcEven); c = __shfl(pk[1][0], srcEven); B0.w[0] = hiKK ? c : a;
            a = __shfl(pk[0][1], srcEven); c = __shfl(pk[1][1], srcEven); B0.w[1] = hiKK ? c : a;
            a = __shfl(pk[0][0], srcOdd);  c = __shfl(pk[1][0], srcOdd);  B0.w[2] = hiKK ? c : a;
            a = __shfl(pk[0][1], srcOdd);  c = __shfl(pk[1][1], srcOdd);  B0.w[3] = hiKK ? c : a;
            a = __shfl(pk[2][0], srcEven); c = __shfl(pk[3][0], srcEven); B1.w[0] = hiKK ? c : a;
            a = __shfl(pk[2][1], srcEven); c = __shfl(pk[3][1], srcEven); B1.w[1] = hiKK ? c : a;
            a = __shfl(pk[2][0], srcOdd);  c = __shfl(pk[3][0], srcOdd);  B1.w[2] = hiKK ? c : a;
            a = __shfl(pk[2][1], srcOdd);  c = __shfl(pk[3][1], srcOdd);  B1.w[3] = hiKK ? c : a;
        }

#pragma unroll
        for (int j = 0; j < 4; j++) {
            const bf16x8 a0 = *(const bf16x8*)&sVt[j * 16 + lr][lc * 8];
            const bf16x8 a1 = *(const bf16x8*)&sVt[j * 16 + lr][32 + lc * 8];
            oacc[j] = MFMA16(a0, B0.v, oacc[j]);
            oacc[j] = MFMA16(a1, B1.v, oacc[j]);
        }
    }

    __syncthreads();
    const float inv = 1.0f / lrow;
#pragma unroll
    for (int j = 0; j < 4; j++)
#pragma unroll
        for (int p = 0; p < 2; p++) {
            const unsigned int w = pack_bf2(oacc[j][2 * p] * inv, oacc[j][2 * p + 1] * inv);
            *(unsigned int*)&sVt[wave * 16 + lr][j * 16 + lc * 4 + 2 * p] = w;
        }
    __syncthreads();
#pragma unroll
    for (int half = 0; half < 2; half++) {
        const int c = lane + 64 * half;
        const int row = c >> 3, ch = c & 7;
        const uint4 o = *(const uint4*)&sVt[wave * 16 + row][ch * 8];
        *(uint4*)&AO[((size_t)b * 2048 + qw + row) * 2048 + h * 64 + ch * 8] = o;
    }
}

// ---------------------------------------------------------------- host
extern "C" void kernel_launch(void* const* d_in, const int* in_sizes, int n_in,
                              void* d_out, int out_size, void* d_ws, size_t ws_size,
                              hipStream_t stream) {
    const float* x  = (const float*)d_in[0];
    const float* fc = (const float*)d_in[1];
    const int* sid  = (const int*)d_in[2];
    const float* wq = (const float*)d_in[3];
    const float* wk = (const float*)d_in[4];
    const float* wv = (const float*)d_in[5];
    const float* wo = (const float*)d_in[6];
    float* out = (float*)d_out;

    unsigned short* xb   = (unsigned short*)d_ws;
    unsigned short* wqkv = xb + (size_t)4096 * 2048;
    unsigned short* wob  = wqkv + (size_t)3072 * 2048;
    unsigned short* Qb   = wob + (size_t)2048 * 2048;
    unsigned short* Kb   = Qb + (size_t)2 * 32 * 2048 * 64;
    unsigned short* Vb   = Kb + (size_t)2 * 8 * 2048 * 64;
    unsigned short* AO   = Vb + (size_t)2 * 8 * 2048 * 64;
    int* dstart = (int*)(AO + (size_t)4096 * 2048);

    cvt_kernel<<<8192, 256, 0, stream>>>(x, xb, 2097152);
    cvt_kernel<<<4096, 256, 0, stream>>>(wq, wqkv, 1048576);
    cvt_kernel<<<1024, 256, 0, stream>>>(wk, wqkv + (size_t)2048 * 2048, 262144);
    cvt_kernel<<<1024, 256, 0, stream>>>(wv, wqkv + (size_t)2560 * 2048, 262144);
    cvt_kernel<<<4096, 256, 0, stream>>>(wo, wob, 1048576);
    docstart_kernel<<<16, 256, 0, stream>>>(sid, dstart);
    gemm_qkv8<<<dim3(192), 512, 0, stream>>>(xb, wqkv, Qb, Kb, Vb);
    rope_kernel<<<20480, 256, 0, stream>>>(Qb, Kb, fc);
    attn_kernel<<<dim3(32, 32, 2), 256, 0, stream>>>(Qb, Kb, Vb, dstart, AO);
    gemm_bt<1><<<dim3(16, 32), 256, 0, stream>>>(AO, wob, 2048, 2048, nullptr, nullptr, nullptr, out);
}

// Round 8
// 216.797 us; speedup vs baseline: 1.1151x; 1.1151x over previous
//
#include <hip/hip_runtime.h>
#include <hip/hip_bf16.h>

typedef __attribute__((ext_vector_type(8))) short bf16x8;
typedef __attribute__((ext_vector_type(4))) float f32x4;

#define MFMA16(A, B, C) __builtin_amdgcn_mfma_f32_16x16x32_bf16(A, B, C, 0, 0, 0)

__device__ __forceinline__ unsigned short f2bf(float f) {
    unsigned int u = __float_as_uint(f);
    u += 0x7fffu + ((u >> 16) & 1u);
    return (unsigned short)(u >> 16);
}
__device__ __forceinline__ float bf2f(unsigned short h) {
    return __uint_as_float(((unsigned int)h) << 16);
}
__device__ __forceinline__ unsigned int pack_bf2(float lo, float hi) {
    __hip_bfloat162 h = __float22bfloat162_rn(make_float2(lo, hi)); // v_cvt_pk_bf16_f32
    return *reinterpret_cast<unsigned int*>(&h);
}

__device__ __forceinline__ void gload_lds16(const void* g, void* l) {
    __builtin_amdgcn_global_load_lds(
        (__attribute__((address_space(1))) unsigned int*)g,
        (__attribute__((address_space(3))) unsigned int*)l, 16, 0, 0);
}

// LDS swizzle for [128 rows][64 bf16] regions (128 B/row): XOR chunk with row&7.
__device__ __forceinline__ int swz128(int by) {
    return by ^ (((by >> 7) & 7) << 4);
}

// ---------------------------------------------------------------- fused converts (1 launch)
__global__ void cvt_all_kernel(const float* __restrict__ x,  const float* __restrict__ wq,
                               const float* __restrict__ wk, const float* __restrict__ wv,
                               const float* __restrict__ wo,
                               unsigned short* __restrict__ xb,
                               unsigned short* __restrict__ wqkv,
                               unsigned short* __restrict__ wob) {
    const int i = blockIdx.x * 256 + threadIdx.x; // 0 .. 4718591 (float4 units)
    const float* src;
    unsigned short* dst;
    int off;
    if (i < 2097152)      { src = x;  dst = xb;   off = i; }
    else if (i < 3145728) { src = wq; dst = wqkv; off = i - 2097152; }
    else if (i < 3407872) { src = wk; dst = wqkv + (size_t)2048 * 2048; off = i - 3145728; }
    else if (i < 3670016) { src = wv; dst = wqkv + (size_t)2560 * 2048; off = i - 3407872; }
    else                  { src = wo; dst = wob;  off = i - 3670016; }
    const float4 v = ((const float4*)src)[off];
    uint2 o;
    o.x = pack_bf2(v.x, v.y);
    o.y = pack_bf2(v.z, v.w);
    ((uint2*)dst)[off] = o;
}

// ---------------------------------------------------------------- doc starts
__global__ void docstart_kernel(const int* __restrict__ sid, int* __restrict__ ds) {
    const int i = blockIdx.x * 256 + threadIdx.x; // 0..4095
    const int b = i >> 11, s = i & 2047;
    const int* row = sid + b * 2048;
    const int v = row[s];
    int lo = 0, hi = s;
    while (lo < hi) { const int mid = (lo + hi) >> 1; if (row[mid] < v) lo = mid + 1; else hi = mid; }
    ds[i] = lo;
}

// ---------------------------------------------------------------- QKV 256x256 8-phase GEMM (round-6 verified)
// + RoPE fused into epilogue (Q and K heads; pair partner via shfl_xor(1)).
#define QKV_K 2048
#define QKV_NT 32
__global__ __launch_bounds__(512, 2) void gemm_qkv8(
    const unsigned short* __restrict__ A,
    const unsigned short* __restrict__ B,
    const float* __restrict__ fc,
    unsigned short* __restrict__ oq,
    unsigned short* __restrict__ ok,
    unsigned short* __restrict__ ov)
{
    __shared__ __align__(16) unsigned short S[2][2][2][8192]; // 128 KiB
    const int tid = threadIdx.x, lane = tid & 63, w = tid >> 6;
    const int wr = w >> 2, wc = w & 3;
    const int lr = lane & 15, lc = lane >> 4;

    // XCD swizzle over 192 blocks (192 % 8 == 0)
    int bid = blockIdx.x;
    bid = (bid & 7) * 24 + (bid >> 3);
    const int m0 = (bid / 12) * 256, n0 = (bid % 12) * 256;

    // staging geometry: linear LDS dest, inverse-swizzled global source (rule #21)
    const int o0 = (w << 11) + (lane << 4);
    const int o1 = o0 + 1024;
    const int v0 = swz128(o0), v1 = swz128(o1);
    const int r0 = v0 >> 7, c0 = (v0 & 127) >> 1;
    const int r1 = v1 >> 7, c1 = (v1 & 127) >> 1;
    const size_t aoff0 = (size_t)(m0 + r0) * QKV_K + c0;
    const size_t aoff1 = (size_t)(m0 + r1) * QKV_K + c1;
    const size_t boff0 = (size_t)(n0 + r0) * QKV_K + c0;
    const size_t boff1 = (size_t)(n0 + r1) * QKV_K + c1;
    const int d0 = o0 >> 1, d1 = o1 >> 1;

    f32x4 acc[2][2][4][2];
#pragma unroll
    for (int a = 0; a < 2; a++)
#pragma unroll
        for (int bq = 0; bq < 2; bq++)
#pragma unroll
            for (int i = 0; i < 4; i++)
#pragma unroll
                for (int j = 0; j < 2; j++) acc[a][bq][i][j] = (f32x4){0.f, 0.f, 0.f, 0.f};

    bf16x8 Af[4][2], Bf0[2][2], Bf1[2][2];

    auto STAGE_A = [&](int bf, int h, int kt) {
        gload_lds16(A + aoff0 + (size_t)h * 128 * QKV_K + (size_t)kt * 64, &S[bf][0][h][d0]);
        gload_lds16(A + aoff1 + (size_t)h * 128 * QKV_K + (size_t)kt * 64, &S[bf][0][h][d1]);
    };
    auto STAGE_B = [&](int bf, int h, int kt) {
        gload_lds16(B + boff0 + (size_t)h * 128 * QKV_K + (size_t)kt * 64, &S[bf][1][h][d0]);
        gload_lds16(B + boff1 + (size_t)h * 128 * QKV_K + (size_t)kt * 64, &S[bf][1][h][d1]);
    };
    auto LDA = [&](int bf, int mh) {
#pragma unroll
        for (int i = 0; i < 4; i++)
#pragma unroll
            for (int kh = 0; kh < 2; kh++) {
                const int by = swz128(((wr * 64 + i * 16 + lr) << 7) + (kh << 6) + (lc << 4));
                Af[i][kh] = *(const bf16x8*)((const char*)&S[bf][0][mh][0] + by);
            }
    };
    auto LDB = [&](int bf, int nh, bf16x8 (&Bf)[2][2]) {
#pragma unroll
        for (int j = 0; j < 2; j++)
#pragma unroll
            for (int kh = 0; kh < 2; kh++) {
                const int by = swz128(((wc * 32 + j * 16 + lr) << 7) + (kh << 6) + (lc << 4));
                Bf[j][kh] = *(const bf16x8*)((const char*)&S[bf][1][nh][0] + by);
            }
    };
    auto QUAD = [&](f32x4 (&ac)[4][2], bf16x8 (&Bf)[2][2]) {
        __builtin_amdgcn_s_setprio(1);
#pragma unroll
        for (int i = 0; i < 4; i++)
#pragma unroll
            for (int j = 0; j < 2; j++)
#pragma unroll
                for (int kh = 0; kh < 2; kh++)
                    ac[i][j] = MFMA16(Af[i][kh], Bf[j][kh], ac[i][j]);
        __builtin_amdgcn_s_setprio(0);
    };

#define BAR() __builtin_amdgcn_s_barrier()
#define LGKM0() asm volatile("s_waitcnt lgkmcnt(0)" ::: "memory")

    // ---- prologue: tile0 (A0,A1,B0,B1)->buf0; A0[1],B1[1],A1[1]->buf1; drain to 3
    STAGE_A(0, 0, 0); STAGE_A(0, 1, 0); STAGE_B(0, 0, 0); STAGE_B(0, 1, 0);
    STAGE_A(1, 0, 1); STAGE_B(1, 1, 1); STAGE_A(1, 1, 1);
    asm volatile("s_waitcnt vmcnt(6)" ::: "memory");
    BAR();

    auto GROUP = [&](int g, int bf) {
        // ph1: quadrant (0,0); stage B0[g+1] -> other buf
        LDA(bf, 0); LDB(bf, 0, Bf0);
        if (g + 1 < QKV_NT) STAGE_B(bf ^ 1, 0, g + 1);
        BAR(); LGKM0();
        QUAD(acc[0][0], Bf0);
        BAR();
        // ph2: (0,1); stage A0[g+2] -> current buf
        LDB(bf, 1, Bf1);
        if (g + 2 < QKV_NT) STAGE_A(bf, 0, g + 2);
        BAR(); LGKM0();
        QUAD(acc[0][1], Bf1);
        BAR();
        // ph3: (1,1); stage B1[g+2] -> current buf
        LDA(bf, 1);
        if (g + 2 < QKV_NT) STAGE_B(bf, 1, g + 2);
        BAR(); LGKM0();
        QUAD(acc[1][1], Bf1);
        BAR();
        // ph4: (1,0); stage A1[g+2] -> current buf
        if (g + 2 < QKV_NT) STAGE_A(bf, 1, g + 2);
        BAR();
        QUAD(acc[1][0], Bf0);
        if (g == QKV_NT - 2) { asm volatile("s_waitcnt vmcnt(0)" ::: "memory"); }
        else                 { asm volatile("s_waitcnt vmcnt(6)" ::: "memory"); }
        BAR();
    };

#pragma unroll 1
    for (int g = 0; g < QKV_NT; g += 2) {
        GROUP(g, 0);
        GROUP(g + 1, 1);
    }

    // ---- epilogue: RoPE (Q,K) fused + scatter into Q:(B,32,S,64), K/V:(B,8,S,64)
#pragma unroll
    for (int mh = 0; mh < 2; mh++)
#pragma unroll
        for (int nh = 0; nh < 2; nh++)
#pragma unroll
            for (int i = 0; i < 4; i++)
#pragma unroll
                for (int j = 0; j < 2; j++) {
                    const int n = n0 + nh * 128 + wc * 32 + j * 16 + lr;
                    const int d = n & 63;
                    const int p = d >> 1;
                    const int hh6 = n >> 6;
                    const bool isV = (n >= 2560); // wave-uniform (n varies only by lr within 16)
#pragma unroll
                    for (int r = 0; r < 4; r++) {
                        const int m = m0 + mh * 128 + wr * 64 + i * 16 + lc * 4 + r;
                        const int bb = m >> 11, s = m & 2047;
                        float v = acc[mh][nh][i][j][r];
                        const float pv = __shfl_xor(v, 1); // partner d^1 lives in lane^1
                        if (!isV) {
                            const float2 cs = *(const float2*)&fc[((s << 5) + p) << 1];
                            v = (d & 1) ? fmaf(v, cs.x, pv * cs.y)
                                        : fmaf(v, cs.x, -pv * cs.y);
                        }
                        const unsigned short val = f2bf(v);
                        if (n < 2048) {
                            oq[((((size_t)bb * 32 + hh6) * 2048 + s) << 6) + d] = val;
                        } else if (n < 2560) {
                            ok[((((size_t)bb * 8 + (hh6 - 32)) * 2048 + s) << 6) + d] = val;
                        } else {
                            ov[((((size_t)bb * 8 + (hh6 - 40)) * 2048 + s) << 6) + d] = val;
                        }
                    }
                }
}
#undef BAR
#undef LGKM0

// ---------------------------------------------------------------- bt-GEMM (m97 structure) for out-proj
template <int EPI>
__global__ __launch_bounds__(256) void gemm_bt(
    const unsigned short* __restrict__ A,
    const unsigned short* __restrict__ B,
    int K, int N,
    unsigned short* __restrict__ oq,
    unsigned short* __restrict__ ok,
    unsigned short* __restrict__ ov,
    float* __restrict__ of)
{
    __shared__ __align__(16) unsigned short sA[128 * 32];
    __shared__ __align__(16) unsigned short sB[128 * 32];
    const int tid = threadIdx.x;
    const int lane = tid & 63, wave = tid >> 6;
    const int wr = wave >> 1, wc = wave & 1;
    const int lr = lane & 15, lc = lane >> 4;

    int bid = blockIdx.y * gridDim.x + blockIdx.x;
    const int cpx = (gridDim.x * gridDim.y) >> 3;
    bid = (bid & 7) * cpx + (bid >> 3);
    const int m0 = (bid / gridDim.x) * 128, n0 = (bid % gridDim.x) * 128;

    f32x4 acc[4][4];
#pragma unroll
    for (int i = 0; i < 4; i++)
#pragma unroll
        for (int j = 0; j < 4; j++) acc[i][j] = (f32x4){0.f, 0.f, 0.f, 0.f};

    const int u0 = tid, u1 = tid + 256;
    for (int k0 = 0; k0 < K; k0 += 32) {
        __syncthreads();
        gload_lds16(A + (size_t)(m0 + (u0 >> 2)) * K + k0 + (u0 & 3) * 8, &sA[u0 * 8]);
        gload_lds16(A + (size_t)(m0 + (u1 >> 2)) * K + k0 + (u1 & 3) * 8, &sA[u1 * 8]);
        gload_lds16(B + (size_t)(n0 + (u0 >> 2)) * K + k0 + (u0 & 3) * 8, &sB[u0 * 8]);
        gload_lds16(B + (size_t)(n0 + (u1 >> 2)) * K + k0 + (u1 & 3) * 8, &sB[u1 * 8]);
        __syncthreads();
        bf16x8 af[4], bfv[4];
#pragma unroll
        for (int i = 0; i < 4; i++) {
            af[i]  = *(const bf16x8*)&sA[(wr * 64 + i * 16 + lr) * 32 + lc * 8];
            bfv[i] = *(const bf16x8*)&sB[(wc * 64 + i * 16 + lr) * 32 + lc * 8];
        }
#pragma unroll
        for (int i = 0; i < 4; i++)
#pragma unroll
            for (int j = 0; j < 4; j++) acc[i][j] = MFMA16(af[i], bfv[j], acc[i][j]);
    }

    if (EPI == 0) {
#pragma unroll
        for (int i = 0; i < 4; i++) {
#pragma unroll
            for (int j = 0; j < 4; j++) {
                const int n = n0 + wc * 64 + j * 16 + lr;
                const int d = n & 63;
#pragma unroll
                for (int r = 0; r < 4; r++) {
                    const int m = m0 + wr * 64 + i * 16 + lc * 4 + r;
                    const int bb = m >> 11, s = m & 2047;
                    const unsigned short val = f2bf(acc[i][j][r]);
                    if (n < 2048) {
                        const int hh = n >> 6;
                        oq[((((size_t)bb * 32 + hh) * 2048 + s) << 6) + d] = val;
                    } else if (n < 2560) {
                        const int hh = (n >> 6) - 32;
                        ok[((((size_t)bb * 8 + hh) * 2048 + s) << 6) + d] = val;
                    } else {
                        const int hh = (n >> 6) - 40;
                        ov[((((size_t)bb * 8 + hh) * 2048 + s) << 6) + d] = val;
                    }
                }
            }
        }
    } else {
#pragma unroll
        for (int i = 0; i < 4; i++)
#pragma unroll
            for (int j = 0; j < 4; j++)
#pragma unroll
                for (int r = 0; r < 4; r++) {
                    const int m = m0 + wr * 64 + i * 16 + lc * 4 + r;
                    const int n = n0 + wc * 64 + j * 16 + lr;
                    of[(size_t)m * N + n] = acc[i][j][r];
                }
    }
}

// ---------------------------------------------------------------- flash attention v4
// v3 + double-buffered K/V with T14 async-stage split: issue t+64 loads before
// compute(t); vmcnt(0)+V-LDS-write after softmax; PV; barrier. HBM hides under softmax.
__global__ __launch_bounds__(256) void attn_kernel(
    const unsigned short* __restrict__ Q,
    const unsigned short* __restrict__ K,
    const unsigned short* __restrict__ V,
    const int* __restrict__ dstart,
    unsigned short* __restrict__ AO)
{
    const int qt = 31 - blockIdx.x; // heavy blocks first
    const int h = blockIdx.y, b = blockIdx.z;
    const int kvh = h >> 2;
    const int tid = threadIdx.x, lane = tid & 63, wave = tid >> 6;
    const int lr = lane & 15, lc = lane >> 4;
    const int q0 = qt * 64;
    const int qw = q0 + wave * 16;

    __shared__ __align__(16) unsigned short sK[2][64 * 64];   // chunk-XOR swizzled
    __shared__ __align__(16) unsigned short sVt[2][64][72];   // V^T, conflict-free writes

    const unsigned short* Qh = Q + (((size_t)b * 32 + h) * 2048) * 64;
    const unsigned short* Kh = K + (((size_t)b * 8 + kvh) * 2048) * 64;
    const unsigned short* Vh = V + (((size_t)b * 8 + kvh) * 2048) * 64;

    const bf16x8 qf0 = *(const bf16x8*)&Qh[(size_t)(qw + lr) * 64 + lc * 8];
    const bf16x8 qf1 = *(const bf16x8*)&Qh[(size_t)(qw + lr) * 64 + 32 + lc * 8];

    const int qglob = qw + lr;
    const int dsl = dstart[b * 2048 + qglob];
    const int ds_wmin = dstart[b * 2048 + qw];
    const int t0 = dstart[b * 2048 + q0] & ~63;

    const int w8 = wave * 8;
    const int slot0 = tid,       kr0 = slot0 >> 3, kc0 = slot0 & 7;
    const int slot1 = tid + 256, kr1 = slot1 >> 3, kc1 = slot1 & 7;

    auto STAGE_K = [&](int t, int c) {
        gload_lds16(Kh + (size_t)(t + kr0) * 64 + ((kc0 ^ (kr0 & 7)) * 8), &sK[c][slot0 * 8]);
        gload_lds16(Kh + (size_t)(t + kr1) * 64 + ((kc1 ^ (kr1 & 7)) * 8), &sK[c][slot1 * 8]);
    };
    auto WRITE_V = [&](const uint4& va, const uint4& vb, int c) {
        const unsigned short* pa = (const unsigned short*)&va;
        const unsigned short* pb = (const unsigned short*)&vb;
#pragma unroll
        for (int e = 0; e < 8; e++) sVt[c][w8 + e][lane] = pa[e];
#pragma unroll
        for (int e = 0; e < 8; e++) sVt[c][32 + w8 + e][lane] = pb[e];
    };

    float mrow = -1e30f, lrow = 0.f;
    f32x4 oacc[4];
#pragma unroll
    for (int j = 0; j < 4; j++) oacc[j] = (f32x4){0.f, 0.f, 0.f, 0.f};

    // ---- prologue: stage tile t0 into buf 0
    STAGE_K(t0, 0);
    {
        const uint4 va = *(const uint4*)&Vh[(size_t)(t0 + lane) * 64 + w8];
        const uint4 vb = *(const uint4*)&Vh[(size_t)(t0 + lane) * 64 + 32 + w8];
        asm volatile("s_waitcnt vmcnt(0)" ::: "memory");
        WRITE_V(va, vb, 0);
    }
    __syncthreads();

    int cb = 0;
    for (int t = t0; t < q0 + 64; t += 64, cb ^= 1) {
        const bool more = (t < q0); // block-uniform
        uint4 va, vb;
        if (more) {
            STAGE_K(t + 64, cb ^ 1);
            va = *(const uint4*)&Vh[(size_t)(t + 64 + lane) * 64 + w8];
            vb = *(const uint4*)&Vh[(size_t)(t + 64 + lane) * 64 + 32 + w8];
        }
        const bool act = !(t > qw + 15 || t + 63 < ds_wmin); // wave-uniform
        union { unsigned int w[4]; bf16x8 v; } B0, B1;

        if (act) {
            // --- QK^T swapped: C[k][q], k = kk*16 + lc*4 + r, q = qw + lr
            f32x4 sc[4];
#pragma unroll
            for (int kk = 0; kk < 4; kk++) {
                const int krow = kk * 16 + lr;
                const bf16x8 kf0 = *(const bf16x8*)&sK[cb][krow * 64 + ((lc ^ (lr & 7)) * 8)];
                const bf16x8 kf1 = *(const bf16x8*)&sK[cb][krow * 64 + (((4 + lc) ^ (lr & 7)) * 8)];
                f32x4 a = (f32x4){0.f, 0.f, 0.f, 0.f};
                a = MFMA16(kf0, qf0, a);
                a = MFMA16(kf1, qf1, a);
                sc[kk] = a;
            }
            // --- mask + scale + in-lane softmax
            float vmax = -3e38f;
#pragma unroll
            for (int kk = 0; kk < 4; kk++)
#pragma unroll
                for (int r = 0; r < 4; r++) {
                    const int kpos = t + kk * 16 + lc * 4 + r;
                    const bool okm = (kpos <= qglob) && (kpos >= dsl);
                    sc[kk][r] = okm ? sc[kk][r] * 0.125f : -3e38f;
                    vmax = fmaxf(vmax, sc[kk][r]);
                }
            vmax = fmaxf(vmax, __shfl_xor(vmax, 16));
            vmax = fmaxf(vmax, __shfl_xor(vmax, 32));
            const float mnew = fmaxf(mrow, vmax);
            const float corr = __expf(mrow - mnew);
            mrow = mnew;

            float rsum = 0.f;
            unsigned int pk[4][2];
#pragma unroll
            for (int kk = 0; kk < 4; kk++) {
                const float p0 = __expf(sc[kk][0] - mnew);
                const float p1 = __expf(sc[kk][1] - mnew);
                const float p2 = __expf(sc[kk][2] - mnew);
                const float p3 = __expf(sc[kk][3] - mnew);
                rsum += (p0 + p1) + (p2 + p3);
                pk[kk][0] = pack_bf2(p0, p1);
                pk[kk][1] = pack_bf2(p2, p3);
            }
            rsum += __shfl_xor(rsum, 16);
            rsum += __shfl_xor(rsum, 32);
            lrow = lrow * corr + rsum;
#pragma unroll
            for (int j = 0; j < 4; j++)
#pragma unroll
                for (int r = 0; r < 4; r++) oacc[j][r] *= corr;

            // --- redistribute P -> PV B-frags (shuffle both kk candidates, cndmask by dest lc>>1)
            const int srcEven = 32 * (lc & 1) + lr;
            const int srcOdd  = srcEven + 16;
            const bool hiKK = (lc & 2) != 0;
            unsigned int a, c;
            a = __shfl(pk[0][0], srcEven); c = __shfl(pk[1][0], srcEven); B0.w[0] = hiKK ? c : a;
            a = __shfl(pk[0][1], srcEven); c = __shfl(pk[1][1], srcEven); B0.w[1] = hiKK ? c : a;
            a = __shfl(pk[0][0], srcOdd);  c = __shfl(pk[1][0], srcOdd);  B0.w[2] = hiKK ? c : a;
            a = __shfl(pk[0][1], srcOdd);  c = __shfl(pk[1][1], srcOdd);  B0.w[3] = hiKK ? c : a;
            a = __shfl(pk[2][0], srcEven); c = __shfl(pk[3][0], srcEven); B1.w[0] = hiKK ? c : a;
            a = __shfl(pk[2][1], srcEven); c = __shfl(pk[3][1], srcEven); B1.w[1] = hiKK ? c : a;
            a = __shfl(pk[2][0], srcOdd);  c = __shfl(pk[3][0], srcOdd);  B1.w[2] = hiKK ? c : a;
            a = __shfl(pk[2][1], srcOdd);  c = __shfl(pk[3][1], srcOdd);  B1.w[3] = hiKK ? c : a;
        }

        if (more) {
            asm volatile("s_waitcnt vmcnt(0)" ::: "memory"); // V(t+64) regs + K(t+64) LDS landed
            WRITE_V(va, vb, cb ^ 1);
        }

        if (act) {
            // --- PV: O^T = V^T x P^T, C[d][q]: d = j*16 + lc*4 + r, q = qw + lr
#pragma unroll
            for (int j = 0; j < 4; j++) {
                const bf16x8 a0 = *(const bf16x8*)&sVt[cb][j * 16 + lr][lc * 8];
                const bf16x8 a1 = *(const bf16x8*)&sVt[cb][j * 16 + lr][32 + lc * 8];
                oacc[j] = MFMA16(a0, B0.v, oacc[j]);
                oacc[j] = MFMA16(a1, B1.v, oacc[j]);
            }
        }
        __syncthreads();
    }

    // --- epilogue: transpose via LDS (reuse sVt[0] rows per wave), coalesced stores
    const float inv = 1.0f / lrow;
#pragma unroll
    for (int j = 0; j < 4; j++)
#pragma unroll
        for (int p = 0; p < 2; p++) {
            const unsigned int w = pack_bf2(oacc[j][2 * p] * inv, oacc[j][2 * p + 1] * inv);
            *(unsigned int*)&sVt[0][wave * 16 + lr][j * 16 + lc * 4 + 2 * p] = w;
        }
    __syncthreads();
#pragma unroll
    for (int half = 0; half < 2; half++) {
        const int c = lane + 64 * half;
        const int row = c >> 3, ch = c & 7;
        const uint4 o = *(const uint4*)&sVt[0][wave * 16 + row][ch * 8];
        *(uint4*)&AO[((size_t)b * 2048 + qw + row) * 2048 + h * 64 + ch * 8] = o;
    }
}

// ---------------------------------------------------------------- host
extern "C" void kernel_launch(void* const* d_in, const int* in_sizes, int n_in,
                              void* d_out, int out_size, void* d_ws, size_t ws_size,
                              hipStream_t stream) {
    const float* x  = (const float*)d_in[0];
    const float* fc = (const float*)d_in[1];
    const int* sid  = (const int*)d_in[2];
    const float* wq = (const float*)d_in[3];
    const float* wk = (const float*)d_in[4];
    const float* wv = (const float*)d_in[5];
    const float* wo = (const float*)d_in[6];
    float* out = (float*)d_out;

    unsigned short* xb   = (unsigned short*)d_ws;
    unsigned short* wqkv = xb + (size_t)4096 * 2048;
    unsigned short* wob  = wqkv + (size_t)3072 * 2048;
    unsigned short* Qb   = wob + (size_t)2048 * 2048;
    unsigned short* Kb   = Qb + (size_t)2 * 32 * 2048 * 64;
    unsigned short* Vb   = Kb + (size_t)2 * 8 * 2048 * 64;
    unsigned short* AO   = Vb + (size_t)2 * 8 * 2048 * 64;
    int* dstart = (int*)(AO + (size_t)4096 * 2048);

    cvt_all_kernel<<<18432, 256, 0, stream>>>(x, wq, wk, wv, wo, xb, wqkv, wob);
    docstart_kernel<<<16, 256, 0, stream>>>(sid, dstart);
    gemm_qkv8<<<dim3(192), 512, 0, stream>>>(xb, wqkv, fc, Qb, Kb, Vb);
    attn_kernel<<<dim3(32, 32, 2), 256, 0, stream>>>(Qb, Kb, Vb, dstart, AO);
    gemm_bt<1><<<dim3(16, 32), 256, 0, stream>>>(AO, wob, 2048, 2048, nullptr, nullptr, nullptr, out);
}

// Round 9
// 200.319 us; speedup vs baseline: 1.2068x; 1.0823x over previous
//
#include <hip/hip_runtime.h>
#include <hip/hip_bf16.h>

typedef __attribute__((ext_vector_type(8))) short bf16x8;
typedef __attribute__((ext_vector_type(4))) float f32x4;

#define MFMA16(A, B, C) __builtin_amdgcn_mfma_f32_16x16x32_bf16(A, B, C, 0, 0, 0)

__device__ __forceinline__ unsigned short f2bf(float f) {
    unsigned int u = __float_as_uint(f);
    u += 0x7fffu + ((u >> 16) & 1u);
    return (unsigned short)(u >> 16);
}
__device__ __forceinline__ float bf2f(unsigned short h) {
    return __uint_as_float(((unsigned int)h) << 16);
}
__device__ __forceinline__ unsigned int pack_bf2(float lo, float hi) {
    __hip_bfloat162 h = __float22bfloat162_rn(make_float2(lo, hi)); // v_cvt_pk_bf16_f32
    return *reinterpret_cast<unsigned int*>(&h);
}

__device__ __forceinline__ void gload_lds16(const void* g, void* l) {
    __builtin_amdgcn_global_load_lds(
        (__attribute__((address_space(1))) unsigned int*)g,
        (__attribute__((address_space(3))) unsigned int*)l, 16, 0, 0);
}

// LDS swizzle for [128 rows][64 bf16] regions (128 B/row): XOR chunk with row&7.
__device__ __forceinline__ int swz128(int by) {
    return by ^ (((by >> 7) & 7) << 4);
}

// ---------------------------------------------------------------- fused converts (1 launch)
__global__ void cvt_all_kernel(const float* __restrict__ x,  const float* __restrict__ wq,
                               const float* __restrict__ wk, const float* __restrict__ wv,
                               const float* __restrict__ wo,
                               unsigned short* __restrict__ xb,
                               unsigned short* __restrict__ wqkv,
                               unsigned short* __restrict__ wob) {
    const int i = blockIdx.x * 256 + threadIdx.x; // 0 .. 4718591 (float4 units)
    const float* src;
    unsigned short* dst;
    int off;
    if (i < 2097152)      { src = x;  dst = xb;   off = i; }
    else if (i < 3145728) { src = wq; dst = wqkv; off = i - 2097152; }
    else if (i < 3407872) { src = wk; dst = wqkv + (size_t)2048 * 2048; off = i - 3145728; }
    else if (i < 3670016) { src = wv; dst = wqkv + (size_t)2560 * 2048; off = i - 3407872; }
    else                  { src = wo; dst = wob;  off = i - 3670016; }
    const float4 v = ((const float4*)src)[off];
    uint2 o;
    o.x = pack_bf2(v.x, v.y);
    o.y = pack_bf2(v.z, v.w);
    ((uint2*)dst)[off] = o;
}

// ---------------------------------------------------------------- doc starts
__global__ void docstart_kernel(const int* __restrict__ sid, int* __restrict__ ds) {
    const int i = blockIdx.x * 256 + threadIdx.x; // 0..4095
    const int b = i >> 11, s = i & 2047;
    const int* row = sid + b * 2048;
    const int v = row[s];
    int lo = 0, hi = s;
    while (lo < hi) { const int mid = (lo + hi) >> 1; if (row[mid] < v) lo = mid + 1; else hi = mid; }
    ds[i] = lo;
}

// ---------------------------------------------------------------- QKV 256x256 8-phase GEMM (round-6 verified, epilogue reverted)
#define QKV_K 2048
#define QKV_NT 32
__global__ __launch_bounds__(512, 2) void gemm_qkv8(
    const unsigned short* __restrict__ A,
    const unsigned short* __restrict__ B,
    unsigned short* __restrict__ oq,
    unsigned short* __restrict__ ok,
    unsigned short* __restrict__ ov)
{
    __shared__ __align__(16) unsigned short S[2][2][2][8192]; // 128 KiB
    const int tid = threadIdx.x, lane = tid & 63, w = tid >> 6;
    const int wr = w >> 2, wc = w & 3;
    const int lr = lane & 15, lc = lane >> 4;

    // XCD swizzle over 192 blocks (192 % 8 == 0)
    int bid = blockIdx.x;
    bid = (bid & 7) * 24 + (bid >> 3);
    const int m0 = (bid / 12) * 256, n0 = (bid % 12) * 256;

    // staging geometry: linear LDS dest, inverse-swizzled global source (rule #21)
    const int o0 = (w << 11) + (lane << 4);
    const int o1 = o0 + 1024;
    const int v0 = swz128(o0), v1 = swz128(o1);
    const int r0 = v0 >> 7, c0 = (v0 & 127) >> 1;
    const int r1 = v1 >> 7, c1 = (v1 & 127) >> 1;
    const size_t aoff0 = (size_t)(m0 + r0) * QKV_K + c0;
    const size_t aoff1 = (size_t)(m0 + r1) * QKV_K + c1;
    const size_t boff0 = (size_t)(n0 + r0) * QKV_K + c0;
    const size_t boff1 = (size_t)(n0 + r1) * QKV_K + c1;
    const int d0 = o0 >> 1, d1 = o1 >> 1;

    f32x4 acc[2][2][4][2];
#pragma unroll
    for (int a = 0; a < 2; a++)
#pragma unroll
        for (int bq = 0; bq < 2; bq++)
#pragma unroll
            for (int i = 0; i < 4; i++)
#pragma unroll
                for (int j = 0; j < 2; j++) acc[a][bq][i][j] = (f32x4){0.f, 0.f, 0.f, 0.f};

    bf16x8 Af[4][2], Bf0[2][2], Bf1[2][2];

    auto STAGE_A = [&](int bf, int h, int kt) {
        gload_lds16(A + aoff0 + (size_t)h * 128 * QKV_K + (size_t)kt * 64, &S[bf][0][h][d0]);
        gload_lds16(A + aoff1 + (size_t)h * 128 * QKV_K + (size_t)kt * 64, &S[bf][0][h][d1]);
    };
    auto STAGE_B = [&](int bf, int h, int kt) {
        gload_lds16(B + boff0 + (size_t)h * 128 * QKV_K + (size_t)kt * 64, &S[bf][1][h][d0]);
        gload_lds16(B + boff1 + (size_t)h * 128 * QKV_K + (size_t)kt * 64, &S[bf][1][h][d1]);
    };
    auto LDA = [&](int bf, int mh) {
#pragma unroll
        for (int i = 0; i < 4; i++)
#pragma unroll
            for (int kh = 0; kh < 2; kh++) {
                const int by = swz128(((wr * 64 + i * 16 + lr) << 7) + (kh << 6) + (lc << 4));
                Af[i][kh] = *(const bf16x8*)((const char*)&S[bf][0][mh][0] + by);
            }
    };
    auto LDB = [&](int bf, int nh, bf16x8 (&Bf)[2][2]) {
#pragma unroll
        for (int j = 0; j < 2; j++)
#pragma unroll
            for (int kh = 0; kh < 2; kh++) {
                const int by = swz128(((wc * 32 + j * 16 + lr) << 7) + (kh << 6) + (lc << 4));
                Bf[j][kh] = *(const bf16x8*)((const char*)&S[bf][1][nh][0] + by);
            }
    };
    auto QUAD = [&](f32x4 (&ac)[4][2], bf16x8 (&Bf)[2][2]) {
        __builtin_amdgcn_s_setprio(1);
#pragma unroll
        for (int i = 0; i < 4; i++)
#pragma unroll
            for (int j = 0; j < 2; j++)
#pragma unroll
                for (int kh = 0; kh < 2; kh++)
                    ac[i][j] = MFMA16(Af[i][kh], Bf[j][kh], ac[i][j]);
        __builtin_amdgcn_s_setprio(0);
    };

#define BAR() __builtin_amdgcn_s_barrier()
#define LGKM0() asm volatile("s_waitcnt lgkmcnt(0)" ::: "memory")

    // ---- prologue: tile0 (A0,A1,B0,B1)->buf0; A0[1],B1[1],A1[1]->buf1; drain to 3
    STAGE_A(0, 0, 0); STAGE_A(0, 1, 0); STAGE_B(0, 0, 0); STAGE_B(0, 1, 0);
    STAGE_A(1, 0, 1); STAGE_B(1, 1, 1); STAGE_A(1, 1, 1);
    asm volatile("s_waitcnt vmcnt(6)" ::: "memory");
    BAR();

    auto GROUP = [&](int g, int bf) {
        // ph1: quadrant (0,0); stage B0[g+1] -> other buf
        LDA(bf, 0); LDB(bf, 0, Bf0);
        if (g + 1 < QKV_NT) STAGE_B(bf ^ 1, 0, g + 1);
        BAR(); LGKM0();
        QUAD(acc[0][0], Bf0);
        BAR();
        // ph2: (0,1); stage A0[g+2] -> current buf
        LDB(bf, 1, Bf1);
        if (g + 2 < QKV_NT) STAGE_A(bf, 0, g + 2);
        BAR(); LGKM0();
        QUAD(acc[0][1], Bf1);
        BAR();
        // ph3: (1,1); stage B1[g+2] -> current buf
        LDA(bf, 1);
        if (g + 2 < QKV_NT) STAGE_B(bf, 1, g + 2);
        BAR(); LGKM0();
        QUAD(acc[1][1], Bf1);
        BAR();
        // ph4: (1,0); stage A1[g+2] -> current buf
        if (g + 2 < QKV_NT) STAGE_A(bf, 1, g + 2);
        BAR();
        QUAD(acc[1][0], Bf0);
        if (g == QKV_NT - 2) { asm volatile("s_waitcnt vmcnt(0)" ::: "memory"); }
        else                 { asm volatile("s_waitcnt vmcnt(6)" ::: "memory"); }
        BAR();
    };

#pragma unroll 1
    for (int g = 0; g < QKV_NT; g += 2) {
        GROUP(g, 0);
        GROUP(g + 1, 1);
    }

    // ---- epilogue (round-6): scatter into Q:(B,32,S,64), K/V:(B,8,S,64) bf16
#pragma unroll
    for (int mh = 0; mh < 2; mh++)
#pragma unroll
        for (int nh = 0; nh < 2; nh++)
#pragma unroll
            for (int i = 0; i < 4; i++)
#pragma unroll
                for (int j = 0; j < 2; j++) {
                    const int n = n0 + nh * 128 + wc * 32 + j * 16 + lr;
                    const int d = n & 63;
                    const int hh6 = n >> 6;
#pragma unroll
                    for (int r = 0; r < 4; r++) {
                        const int m = m0 + mh * 128 + wr * 64 + i * 16 + lc * 4 + r;
                        const int bb = m >> 11, s = m & 2047;
                        const unsigned short val = f2bf(acc[mh][nh][i][j][r]);
                        if (n < 2048) {
                            oq[((((size_t)bb * 32 + hh6) * 2048 + s) << 6) + d] = val;
                        } else if (n < 2560) {
                            ok[((((size_t)bb * 8 + (hh6 - 32)) * 2048 + s) << 6) + d] = val;
                        } else {
                            ov[((((size_t)bb * 8 + (hh6 - 40)) * 2048 + s) << 6) + d] = val;
                        }
                    }
                }
}
#undef BAR
#undef LGKM0

// ---------------------------------------------------------------- RoPE, vectorized 4 pairs/thread
// thread j: g = j&7 (8-d-chunk), s = (j>>3)&2047, bh = j>>14; Q then K.
__global__ void rope_kernel(unsigned short* __restrict__ Qb,
                            unsigned short* __restrict__ Kb,
                            const float* __restrict__ fc)
{
    const int NQ = 64 * 2048 * 8; // Q thread count (2*32 heads)
    int j = blockIdx.x * 256 + threadIdx.x;
    unsigned short* base;
    if (j < NQ) base = Qb;
    else { base = Kb; j -= NQ; }
    const int g = j & 7, s = (j >> 3) & 2047, bh = j >> 14;
    const size_t off = (((size_t)bh * 2048 + s) << 6) + g * 8;
    uint4 u = *(uint4*)&base[off];
    const float4 cs0 = *(const float4*)&fc[((s << 5) + g * 4) << 1];     // c0 s0 c1 s1
    const float4 cs1 = *(const float4*)&fc[(((s << 5) + g * 4) << 1) + 4]; // c2 s2 c3 s3
    unsigned int* uw = (unsigned int*)&u;
    float c[4] = {cs0.x, cs0.z, cs1.x, cs1.z};
    float sn[4] = {cs0.y, cs0.w, cs1.y, cs1.w};
#pragma unroll
    for (int q = 0; q < 4; q++) {
        const float t0 = bf2f((unsigned short)(uw[q] & 0xffffu));
        const float t1 = bf2f((unsigned short)(uw[q] >> 16));
        uw[q] = pack_bf2(fmaf(t0, c[q], -t1 * sn[q]), fmaf(t0, sn[q], t1 * c[q]));
    }
    *(uint4*)&base[off] = u;
}

// ---------------------------------------------------------------- bt-GEMM (m97 structure) for out-proj
template <int EPI>
__global__ __launch_bounds__(256) void gemm_bt(
    const unsigned short* __restrict__ A,
    const unsigned short* __restrict__ B,
    int K, int N,
    unsigned short* __restrict__ oq,
    unsigned short* __restrict__ ok,
    unsigned short* __restrict__ ov,
    float* __restrict__ of)
{
    __shared__ __align__(16) unsigned short sA[128 * 32];
    __shared__ __align__(16) unsigned short sB[128 * 32];
    const int tid = threadIdx.x;
    const int lane = tid & 63, wave = tid >> 6;
    const int wr = wave >> 1, wc = wave & 1;
    const int lr = lane & 15, lc = lane >> 4;

    int bid = blockIdx.y * gridDim.x + blockIdx.x;
    const int cpx = (gridDim.x * gridDim.y) >> 3;
    bid = (bid & 7) * cpx + (bid >> 3);
    const int m0 = (bid / gridDim.x) * 128, n0 = (bid % gridDim.x) * 128;

    f32x4 acc[4][4];
#pragma unroll
    for (int i = 0; i < 4; i++)
#pragma unroll
        for (int j = 0; j < 4; j++) acc[i][j] = (f32x4){0.f, 0.f, 0.f, 0.f};

    const int u0 = tid, u1 = tid + 256;
    for (int k0 = 0; k0 < K; k0 += 32) {
        __syncthreads();
        gload_lds16(A + (size_t)(m0 + (u0 >> 2)) * K + k0 + (u0 & 3) * 8, &sA[u0 * 8]);
        gload_lds16(A + (size_t)(m0 + (u1 >> 2)) * K + k0 + (u1 & 3) * 8, &sA[u1 * 8]);
        gload_lds16(B + (size_t)(n0 + (u0 >> 2)) * K + k0 + (u0 & 3) * 8, &sB[u0 * 8]);
        gload_lds16(B + (size_t)(n0 + (u1 >> 2)) * K + k0 + (u1 & 3) * 8, &sB[u1 * 8]);
        __syncthreads();
        bf16x8 af[4], bfv[4];
#pragma unroll
        for (int i = 0; i < 4; i++) {
            af[i]  = *(const bf16x8*)&sA[(wr * 64 + i * 16 + lr) * 32 + lc * 8];
            bfv[i] = *(const bf16x8*)&sB[(wc * 64 + i * 16 + lr) * 32 + lc * 8];
        }
#pragma unroll
        for (int i = 0; i < 4; i++)
#pragma unroll
            for (int j = 0; j < 4; j++) acc[i][j] = MFMA16(af[i], bfv[j], acc[i][j]);
    }

    if (EPI == 0) {
#pragma unroll
        for (int i = 0; i < 4; i++) {
#pragma unroll
            for (int j = 0; j < 4; j++) {
                const int n = n0 + wc * 64 + j * 16 + lr;
                const int d = n & 63;
#pragma unroll
                for (int r = 0; r < 4; r++) {
                    const int m = m0 + wr * 64 + i * 16 + lc * 4 + r;
                    const int bb = m >> 11, s = m & 2047;
                    const unsigned short val = f2bf(acc[i][j][r]);
                    if (n < 2048) {
                        const int hh = n >> 6;
                        oq[((((size_t)bb * 32 + hh) * 2048 + s) << 6) + d] = val;
                    } else if (n < 2560) {
                        const int hh = (n >> 6) - 32;
                        ok[((((size_t)bb * 8 + hh) * 2048 + s) << 6) + d] = val;
                    } else {
                        const int hh = (n >> 6) - 40;
                        ov[((((size_t)bb * 8 + hh) * 2048 + s) << 6) + d] = val;
                    }
                }
            }
        }
    } else {
#pragma unroll
        for (int i = 0; i < 4; i++)
#pragma unroll
            for (int j = 0; j < 4; j++)
#pragma unroll
                for (int r = 0; r < 4; r++) {
                    const int m = m0 + wr * 64 + i * 16 + lc * 4 + r;
                    const int n = n0 + wc * 64 + j * 16 + lr;
                    of[(size_t)m * N + n] = acc[i][j][r];
                }
    }
}

// ---------------------------------------------------------------- flash attention v4 (round-8 verified)
__global__ __launch_bounds__(256) void attn_kernel(
    const unsigned short* __restrict__ Q,
    const unsigned short* __restrict__ K,
    const unsigned short* __restrict__ V,
    const int* __restrict__ dstart,
    unsigned short* __restrict__ AO)
{
    const int qt = 31 - blockIdx.x; // heavy blocks first
    const int h = blockIdx.y, b = blockIdx.z;
    const int kvh = h >> 2;
    const int tid = threadIdx.x, lane = tid & 63, wave = tid >> 6;
    const int lr = lane & 15, lc = lane >> 4;
    const int q0 = qt * 64;
    const int qw = q0 + wave * 16;

    __shared__ __align__(16) unsigned short sK[2][64 * 64];   // chunk-XOR swizzled
    __shared__ __align__(16) unsigned short sVt[2][64][72];   // V^T, conflict-free writes

    const unsigned short* Qh = Q + (((size_t)b * 32 + h) * 2048) * 64;
    const unsigned short* Kh = K + (((size_t)b * 8 + kvh) * 2048) * 64;
    const unsigned short* Vh = V + (((size_t)b * 8 + kvh) * 2048) * 64;

    const bf16x8 qf0 = *(const bf16x8*)&Qh[(size_t)(qw + lr) * 64 + lc * 8];
    const bf16x8 qf1 = *(const bf16x8*)&Qh[(size_t)(qw + lr) * 64 + 32 + lc * 8];

    const int qglob = qw + lr;
    const int dsl = dstart[b * 2048 + qglob];
    const int ds_wmin = dstart[b * 2048 + qw];
    const int t0 = dstart[b * 2048 + q0] & ~63;

    const int w8 = wave * 8;
    const int slot0 = tid,       kr0 = slot0 >> 3, kc0 = slot0 & 7;
    const int slot1 = tid + 256, kr1 = slot1 >> 3, kc1 = slot1 & 7;

    auto STAGE_K = [&](int t, int c) {
        gload_lds16(Kh + (size_t)(t + kr0) * 64 + ((kc0 ^ (kr0 & 7)) * 8), &sK[c][slot0 * 8]);
        gload_lds16(Kh + (size_t)(t + kr1) * 64 + ((kc1 ^ (kr1 & 7)) * 8), &sK[c][slot1 * 8]);
    };
    auto WRITE_V = [&](const uint4& va, const uint4& vb, int c) {
        const unsigned short* pa = (const unsigned short*)&va;
        const unsigned short* pb = (const unsigned short*)&vb;
#pragma unroll
        for (int e = 0; e < 8; e++) sVt[c][w8 + e][lane] = pa[e];
#pragma unroll
        for (int e = 0; e < 8; e++) sVt[c][32 + w8 + e][lane] = pb[e];
    };

    float mrow = -1e30f, lrow = 0.f;
    f32x4 oacc[4];
#pragma unroll
    for (int j = 0; j < 4; j++) oacc[j] = (f32x4){0.f, 0.f, 0.f, 0.f};

    // ---- prologue: stage tile t0 into buf 0
    STAGE_K(t0, 0);
    {
        const uint4 va = *(const uint4*)&Vh[(size_t)(t0 + lane) * 64 + w8];
        const uint4 vb = *(const uint4*)&Vh[(size_t)(t0 + lane) * 64 + 32 + w8];
        asm volatile("s_waitcnt vmcnt(0)" ::: "memory");
        WRITE_V(va, vb, 0);
    }
    __syncthreads();

    int cb = 0;
    for (int t = t0; t < q0 + 64; t += 64, cb ^= 1) {
        const bool more = (t < q0); // block-uniform
        uint4 va, vb;
        if (more) {
            STAGE_K(t + 64, cb ^ 1);
            va = *(const uint4*)&Vh[(size_t)(t + 64 + lane) * 64 + w8];
            vb = *(const uint4*)&Vh[(size_t)(t + 64 + lane) * 64 + 32 + w8];
        }
        const bool act = !(t > qw + 15 || t + 63 < ds_wmin); // wave-uniform
        union { unsigned int w[4]; bf16x8 v; } B0, B1;

        if (act) {
            // --- QK^T swapped: C[k][q], k = kk*16 + lc*4 + r, q = qw + lr
            f32x4 sc[4];
#pragma unroll
            for (int kk = 0; kk < 4; kk++) {
                const int krow = kk * 16 + lr;
                const bf16x8 kf0 = *(const bf16x8*)&sK[cb][krow * 64 + ((lc ^ (lr & 7)) * 8)];
                const bf16x8 kf1 = *(const bf16x8*)&sK[cb][krow * 64 + (((4 + lc) ^ (lr & 7)) * 8)];
                f32x4 a = (f32x4){0.f, 0.f, 0.f, 0.f};
                a = MFMA16(kf0, qf0, a);
                a = MFMA16(kf1, qf1, a);
                sc[kk] = a;
            }
            // --- mask + scale + in-lane softmax
            float vmax = -3e38f;
#pragma unroll
            for (int kk = 0; kk < 4; kk++)
#pragma unroll
                for (int r = 0; r < 4; r++) {
                    const int kpos = t + kk * 16 + lc * 4 + r;
                    const bool okm = (kpos <= qglob) && (kpos >= dsl);
                    sc[kk][r] = okm ? sc[kk][r] * 0.125f : -3e38f;
                    vmax = fmaxf(vmax, sc[kk][r]);
                }
            vmax = fmaxf(vmax, __shfl_xor(vmax, 16));
            vmax = fmaxf(vmax, __shfl_xor(vmax, 32));
            const float mnew = fmaxf(mrow, vmax);
            const float corr = __expf(mrow - mnew);
            mrow = mnew;

            float rsum = 0.f;
            unsigned int pk[4][2];
#pragma unroll
            for (int kk = 0; kk < 4; kk++) {
                const float p0 = __expf(sc[kk][0] - mnew);
                const float p1 = __expf(sc[kk][1] - mnew);
                const float p2 = __expf(sc[kk][2] - mnew);
                const float p3 = __expf(sc[kk][3] - mnew);
                rsum += (p0 + p1) + (p2 + p3);
                pk[kk][0] = pack_bf2(p0, p1);
                pk[kk][1] = pack_bf2(p2, p3);
            }
            rsum += __shfl_xor(rsum, 16);
            rsum += __shfl_xor(rsum, 32);
            lrow = lrow * corr + rsum;
#pragma unroll
            for (int j = 0; j < 4; j++)
#pragma unroll
                for (int r = 0; r < 4; r++) oacc[j][r] *= corr;

            // --- redistribute P -> PV B-frags (shuffle both kk candidates, cndmask by dest lc>>1)
            const int srcEven = 32 * (lc & 1) + lr;
            const int srcOdd  = srcEven + 16;
            const bool hiKK = (lc & 2) != 0;
            unsigned int a, c;
            a = __shfl(pk[0][0], srcEven); c = __shfl(pk[1][0], srcEven); B0.w[0] = hiKK ? c : a;
            a = __shfl(pk[0][1], srcEven); c = __shfl(pk[1][1], srcEven); B0.w[1] = hiKK ? c : a;
            a = __shfl(pk[0][0], srcOdd);  c = __shfl(pk[1][0], srcOdd);  B0.w[2] = hiKK ? c : a;
            a = __shfl(pk[0][1], srcOdd);  c = __shfl(pk[1][1], srcOdd);  B0.w[3] = hiKK ? c : a;
            a = __shfl(pk[2][0], srcEven); c = __shfl(pk[3][0], srcEven); B1.w[0] = hiKK ? c : a;
            a = __shfl(pk[2][1], srcEven); c = __shfl(pk[3][1], srcEven); B1.w[1] = hiKK ? c : a;
            a = __shfl(pk[2][0], srcOdd);  c = __shfl(pk[3][0], srcOdd);  B1.w[2] = hiKK ? c : a;
            a = __shfl(pk[2][1], srcOdd);  c = __shfl(pk[3][1], srcOdd);  B1.w[3] = hiKK ? c : a;
        }

        if (more) {
            asm volatile("s_waitcnt vmcnt(0)" ::: "memory"); // V(t+64) regs + K(t+64) LDS landed
            WRITE_V(va, vb, cb ^ 1);
        }

        if (act) {
            // --- PV: O^T = V^T x P^T, C[d][q]: d = j*16 + lc*4 + r, q = qw + lr
#pragma unroll
            for (int j = 0; j < 4; j++) {
                const bf16x8 a0 = *(const bf16x8*)&sVt[cb][j * 16 + lr][lc * 8];
                const bf16x8 a1 = *(const bf16x8*)&sVt[cb][j * 16 + lr][32 + lc * 8];
                oacc[j] = MFMA16(a0, B0.v, oacc[j]);
                oacc[j] = MFMA16(a1, B1.v, oacc[j]);
            }
        }
        __syncthreads();
    }

    // --- epilogue: transpose via LDS (reuse sVt[0] rows per wave), coalesced stores
    const float inv = 1.0f / lrow;
#pragma unroll
    for (int j = 0; j < 4; j++)
#pragma unroll
        for (int p = 0; p < 2; p++) {
            const unsigned int w = pack_bf2(oacc[j][2 * p] * inv, oacc[j][2 * p + 1] * inv);
            *(unsigned int*)&sVt[0][wave * 16 + lr][j * 16 + lc * 4 + 2 * p] = w;
        }
    __syncthreads();
#pragma unroll
    for (int half = 0; half < 2; half++) {
        const int c = lane + 64 * half;
        const int row = c >> 3, ch = c & 7;
        const uint4 o = *(const uint4*)&sVt[0][wave * 16 + row][ch * 8];
        *(uint4*)&AO[((size_t)b * 2048 + qw + row) * 2048 + h * 64 + ch * 8] = o;
    }
}

// ---------------------------------------------------------------- host
extern "C" void kernel_launch(void* const* d_in, const int* in_sizes, int n_in,
                              void* d_out, int out_size, void* d_ws, size_t ws_size,
                              hipStream_t stream) {
    const float* x  = (const float*)d_in[0];
    const float* fc = (const float*)d_in[1];
    const int* sid  = (const int*)d_in[2];
    const float* wq = (const float*)d_in[3];
    const float* wk = (const float*)d_in[4];
    const float* wv = (const float*)d_in[5];
    const float* wo = (const float*)d_in[6];
    float* out = (float*)d_out;

    unsigned short* xb   = (unsigned short*)d_ws;
    unsigned short* wqkv = xb + (size_t)4096 * 2048;
    unsigned short* wob  = wqkv + (size_t)3072 * 2048;
    unsigned short* Qb   = wob + (size_t)2048 * 2048;
    unsigned short* Kb   = Qb + (size_t)2 * 32 * 2048 * 64;
    unsigned short* Vb   = Kb + (size_t)2 * 8 * 2048 * 64;
    unsigned short* AO   = Vb + (size_t)2 * 8 * 2048 * 64;
    int* dstart = (int*)(AO + (size_t)4096 * 2048);

    cvt_all_kernel<<<18432, 256, 0, stream>>>(x, wq, wk, wv, wo, xb, wqkv, wob);
    docstart_kernel<<<16, 256, 0, stream>>>(sid, dstart);
    gemm_qkv8<<<dim3(192), 512, 0, stream>>>(xb, wqkv, Qb, Kb, Vb);
    rope_kernel<<<5120, 256, 0, stream>>>(Qb, Kb, fc);
    attn_kernel<<<dim3(32, 32, 2), 256, 0, stream>>>(Qb, Kb, Vb, dstart, AO);
    gemm_bt<1><<<dim3(16, 32), 256, 0, stream>>>(AO, wob, 2048, 2048, nullptr, nullptr, nullptr, out);
}

// Round 10
// 194.893 us; speedup vs baseline: 1.2404x; 1.0278x over previous
//
#include <hip/hip_runtime.h>
#include <hip/hip_bf16.h>

typedef __attribute__((ext_vector_type(8))) short bf16x8;
typedef __attribute__((ext_vector_type(4))) float f32x4;

#define MFMA16(A, B, C) __builtin_amdgcn_mfma_f32_16x16x32_bf16(A, B, C, 0, 0, 0)

__device__ __forceinline__ unsigned short f2bf(float f) {
    unsigned int u = __float_as_uint(f);
    u += 0x7fffu + ((u >> 16) & 1u);
    return (unsigned short)(u >> 16);
}
__device__ __forceinline__ float bf2f(unsigned short h) {
    return __uint_as_float(((unsigned int)h) << 16);
}
__device__ __forceinline__ unsigned int pack_bf2(float lo, float hi) {
    __hip_bfloat162 h = __float22bfloat162_rn(make_float2(lo, hi)); // v_cvt_pk_bf16_f32
    return *reinterpret_cast<unsigned int*>(&h);
}

__device__ __forceinline__ void gload_lds16(const void* g, void* l) {
    __builtin_amdgcn_global_load_lds(
        (__attribute__((address_space(1))) unsigned int*)g,
        (__attribute__((address_space(3))) unsigned int*)l, 16, 0, 0);
}

// LDS swizzle for [128 rows][64 bf16] regions (128 B/row): XOR chunk with row&7.
__device__ __forceinline__ int swz128(int by) {
    return by ^ (((by >> 7) & 7) << 4);
}

// ---------------------------------------------------------------- fused converts (1 launch)
__global__ void cvt_all_kernel(const float* __restrict__ x,  const float* __restrict__ wq,
                               const float* __restrict__ wk, const float* __restrict__ wv,
                               const float* __restrict__ wo,
                               unsigned short* __restrict__ xb,
                               unsigned short* __restrict__ wqkv,
                               unsigned short* __restrict__ wob) {
    const int i = blockIdx.x * 256 + threadIdx.x; // 0 .. 4718591 (float4 units)
    const float* src;
    unsigned short* dst;
    int off;
    if (i < 2097152)      { src = x;  dst = xb;   off = i; }
    else if (i < 3145728) { src = wq; dst = wqkv; off = i - 2097152; }
    else if (i < 3407872) { src = wk; dst = wqkv + (size_t)2048 * 2048; off = i - 3145728; }
    else if (i < 3670016) { src = wv; dst = wqkv + (size_t)2560 * 2048; off = i - 3407872; }
    else                  { src = wo; dst = wob;  off = i - 3670016; }
    const float4 v = ((const float4*)src)[off];
    uint2 o;
    o.x = pack_bf2(v.x, v.y);
    o.y = pack_bf2(v.z, v.w);
    ((uint2*)dst)[off] = o;
}

// ---------------------------------------------------------------- doc starts
__global__ void docstart_kernel(const int* __restrict__ sid, int* __restrict__ ds) {
    const int i = blockIdx.x * 256 + threadIdx.x; // 0..4095
    const int b = i >> 11, s = i & 2047;
    const int* row = sid + b * 2048;
    const int v = row[s];
    int lo = 0, hi = s;
    while (lo < hi) { const int mid = (lo + hi) >> 1; if (row[mid] < v) lo = mid + 1; else hi = mid; }
    ds[i] = lo;
}

// ---------------------------------------------------------------- QKV 256x256 8-phase GEMM (round-6/9 verified, frozen)
#define QKV_K 2048
#define QKV_NT 32
__global__ __launch_bounds__(512, 2) void gemm_qkv8(
    const unsigned short* __restrict__ A,
    const unsigned short* __restrict__ B,
    unsigned short* __restrict__ oq,
    unsigned short* __restrict__ ok,
    unsigned short* __restrict__ ov)
{
    __shared__ __align__(16) unsigned short S[2][2][2][8192]; // 128 KiB
    const int tid = threadIdx.x, lane = tid & 63, w = tid >> 6;
    const int wr = w >> 2, wc = w & 3;
    const int lr = lane & 15, lc = lane >> 4;

    // XCD swizzle over 192 blocks (192 % 8 == 0)
    int bid = blockIdx.x;
    bid = (bid & 7) * 24 + (bid >> 3);
    const int m0 = (bid / 12) * 256, n0 = (bid % 12) * 256;

    // staging geometry: linear LDS dest, inverse-swizzled global source (rule #21)
    const int o0 = (w << 11) + (lane << 4);
    const int o1 = o0 + 1024;
    const int v0 = swz128(o0), v1 = swz128(o1);
    const int r0 = v0 >> 7, c0 = (v0 & 127) >> 1;
    const int r1 = v1 >> 7, c1 = (v1 & 127) >> 1;
    const size_t aoff0 = (size_t)(m0 + r0) * QKV_K + c0;
    const size_t aoff1 = (size_t)(m0 + r1) * QKV_K + c1;
    const size_t boff0 = (size_t)(n0 + r0) * QKV_K + c0;
    const size_t boff1 = (size_t)(n0 + r1) * QKV_K + c1;
    const int d0 = o0 >> 1, d1 = o1 >> 1;

    f32x4 acc[2][2][4][2];
#pragma unroll
    for (int a = 0; a < 2; a++)
#pragma unroll
        for (int bq = 0; bq < 2; bq++)
#pragma unroll
            for (int i = 0; i < 4; i++)
#pragma unroll
                for (int j = 0; j < 2; j++) acc[a][bq][i][j] = (f32x4){0.f, 0.f, 0.f, 0.f};

    bf16x8 Af[4][2], Bf0[2][2], Bf1[2][2];

    auto STAGE_A = [&](int bf, int h, int kt) {
        gload_lds16(A + aoff0 + (size_t)h * 128 * QKV_K + (size_t)kt * 64, &S[bf][0][h][d0]);
        gload_lds16(A + aoff1 + (size_t)h * 128 * QKV_K + (size_t)kt * 64, &S[bf][0][h][d1]);
    };
    auto STAGE_B = [&](int bf, int h, int kt) {
        gload_lds16(B + boff0 + (size_t)h * 128 * QKV_K + (size_t)kt * 64, &S[bf][1][h][d0]);
        gload_lds16(B + boff1 + (size_t)h * 128 * QKV_K + (size_t)kt * 64, &S[bf][1][h][d1]);
    };
    auto LDA = [&](int bf, int mh) {
#pragma unroll
        for (int i = 0; i < 4; i++)
#pragma unroll
            for (int kh = 0; kh < 2; kh++) {
                const int by = swz128(((wr * 64 + i * 16 + lr) << 7) + (kh << 6) + (lc << 4));
                Af[i][kh] = *(const bf16x8*)((const char*)&S[bf][0][mh][0] + by);
            }
    };
    auto LDB = [&](int bf, int nh, bf16x8 (&Bf)[2][2]) {
#pragma unroll
        for (int j = 0; j < 2; j++)
#pragma unroll
            for (int kh = 0; kh < 2; kh++) {
                const int by = swz128(((wc * 32 + j * 16 + lr) << 7) + (kh << 6) + (lc << 4));
                Bf[j][kh] = *(const bf16x8*)((const char*)&S[bf][1][nh][0] + by);
            }
    };
    auto QUAD = [&](f32x4 (&ac)[4][2], bf16x8 (&Bf)[2][2]) {
        __builtin_amdgcn_s_setprio(1);
#pragma unroll
        for (int i = 0; i < 4; i++)
#pragma unroll
            for (int j = 0; j < 2; j++)
#pragma unroll
                for (int kh = 0; kh < 2; kh++)
                    ac[i][j] = MFMA16(Af[i][kh], Bf[j][kh], ac[i][j]);
        __builtin_amdgcn_s_setprio(0);
    };

#define BAR() __builtin_amdgcn_s_barrier()
#define LGKM0() asm volatile("s_waitcnt lgkmcnt(0)" ::: "memory")

    // ---- prologue: tile0 (A0,A1,B0,B1)->buf0; A0[1],B1[1],A1[1]->buf1; drain to 3
    STAGE_A(0, 0, 0); STAGE_A(0, 1, 0); STAGE_B(0, 0, 0); STAGE_B(0, 1, 0);
    STAGE_A(1, 0, 1); STAGE_B(1, 1, 1); STAGE_A(1, 1, 1);
    asm volatile("s_waitcnt vmcnt(6)" ::: "memory");
    BAR();

    auto GROUP = [&](int g, int bf) {
        // ph1: quadrant (0,0); stage B0[g+1] -> other buf
        LDA(bf, 0); LDB(bf, 0, Bf0);
        if (g + 1 < QKV_NT) STAGE_B(bf ^ 1, 0, g + 1);
        BAR(); LGKM0();
        QUAD(acc[0][0], Bf0);
        BAR();
        // ph2: (0,1); stage A0[g+2] -> current buf
        LDB(bf, 1, Bf1);
        if (g + 2 < QKV_NT) STAGE_A(bf, 0, g + 2);
        BAR(); LGKM0();
        QUAD(acc[0][1], Bf1);
        BAR();
        // ph3: (1,1); stage B1[g+2] -> current buf
        LDA(bf, 1);
        if (g + 2 < QKV_NT) STAGE_B(bf, 1, g + 2);
        BAR(); LGKM0();
        QUAD(acc[1][1], Bf1);
        BAR();
        // ph4: (1,0); stage A1[g+2] -> current buf
        if (g + 2 < QKV_NT) STAGE_A(bf, 1, g + 2);
        BAR();
        QUAD(acc[1][0], Bf0);
        if (g == QKV_NT - 2) { asm volatile("s_waitcnt vmcnt(0)" ::: "memory"); }
        else                 { asm volatile("s_waitcnt vmcnt(6)" ::: "memory"); }
        BAR();
    };

#pragma unroll 1
    for (int g = 0; g < QKV_NT; g += 2) {
        GROUP(g, 0);
        GROUP(g + 1, 1);
    }

    // ---- epilogue: scatter into Q:(B,32,S,64), K/V:(B,8,S,64) bf16
#pragma unroll
    for (int mh = 0; mh < 2; mh++)
#pragma unroll
        for (int nh = 0; nh < 2; nh++)
#pragma unroll
            for (int i = 0; i < 4; i++)
#pragma unroll
                for (int j = 0; j < 2; j++) {
                    const int n = n0 + nh * 128 + wc * 32 + j * 16 + lr;
                    const int d = n & 63;
                    const int hh6 = n >> 6;
#pragma unroll
                    for (int r = 0; r < 4; r++) {
                        const int m = m0 + mh * 128 + wr * 64 + i * 16 + lc * 4 + r;
                        const int bb = m >> 11, s = m & 2047;
                        const unsigned short val = f2bf(acc[mh][nh][i][j][r]);
                        if (n < 2048) {
                            oq[((((size_t)bb * 32 + hh6) * 2048 + s) << 6) + d] = val;
                        } else if (n < 2560) {
                            ok[((((size_t)bb * 8 + (hh6 - 32)) * 2048 + s) << 6) + d] = val;
                        } else {
                            ov[((((size_t)bb * 8 + (hh6 - 40)) * 2048 + s) << 6) + d] = val;
                        }
                    }
                }
}
#undef BAR
#undef LGKM0

// ---------------------------------------------------------------- RoPE, vectorized 4 pairs/thread
__global__ void rope_kernel(unsigned short* __restrict__ Qb,
                            unsigned short* __restrict__ Kb,
                            const float* __restrict__ fc)
{
    const int NQ = 64 * 2048 * 8; // Q thread count (2*32 heads)
    int j = blockIdx.x * 256 + threadIdx.x;
    unsigned short* base;
    if (j < NQ) base = Qb;
    else { base = Kb; j -= NQ; }
    const int g = j & 7, s = (j >> 3) & 2047, bh = j >> 14;
    const size_t off = (((size_t)bh * 2048 + s) << 6) + g * 8;
    uint4 u = *(uint4*)&base[off];
    const float4 cs0 = *(const float4*)&fc[((s << 5) + g * 4) << 1];       // c0 s0 c1 s1
    const float4 cs1 = *(const float4*)&fc[(((s << 5) + g * 4) << 1) + 4]; // c2 s2 c3 s3
    unsigned int* uw = (unsigned int*)&u;
    float c[4] = {cs0.x, cs0.z, cs1.x, cs1.z};
    float sn[4] = {cs0.y, cs0.w, cs1.y, cs1.w};
#pragma unroll
    for (int q = 0; q < 4; q++) {
        const float t0 = bf2f((unsigned short)(uw[q] & 0xffffu));
        const float t1 = bf2f((unsigned short)(uw[q] >> 16));
        uw[q] = pack_bf2(fmaf(t0, c[q], -t1 * sn[q]), fmaf(t0, sn[q], t1 * c[q]));
    }
    *(uint4*)&base[off] = u;
}

// ---------------------------------------------------------------- bt-GEMM (m97 structure) for out-proj
template <int EPI>
__global__ __launch_bounds__(256) void gemm_bt(
    const unsigned short* __restrict__ A,
    const unsigned short* __restrict__ B,
    int K, int N,
    unsigned short* __restrict__ oq,
    unsigned short* __restrict__ ok,
    unsigned short* __restrict__ ov,
    float* __restrict__ of)
{
    __shared__ __align__(16) unsigned short sA[128 * 32];
    __shared__ __align__(16) unsigned short sB[128 * 32];
    const int tid = threadIdx.x;
    const int lane = tid & 63, wave = tid >> 6;
    const int wr = wave >> 1, wc = wave & 1;
    const int lr = lane & 15, lc = lane >> 4;

    int bid = blockIdx.y * gridDim.x + blockIdx.x;
    const int cpx = (gridDim.x * gridDim.y) >> 3;
    bid = (bid & 7) * cpx + (bid >> 3);
    const int m0 = (bid / gridDim.x) * 128, n0 = (bid % gridDim.x) * 128;

    f32x4 acc[4][4];
#pragma unroll
    for (int i = 0; i < 4; i++)
#pragma unroll
        for (int j = 0; j < 4; j++) acc[i][j] = (f32x4){0.f, 0.f, 0.f, 0.f};

    const int u0 = tid, u1 = tid + 256;
    for (int k0 = 0; k0 < K; k0 += 32) {
        __syncthreads();
        gload_lds16(A + (size_t)(m0 + (u0 >> 2)) * K + k0 + (u0 & 3) * 8, &sA[u0 * 8]);
        gload_lds16(A + (size_t)(m0 + (u1 >> 2)) * K + k0 + (u1 & 3) * 8, &sA[u1 * 8]);
        gload_lds16(B + (size_t)(n0 + (u0 >> 2)) * K + k0 + (u0 & 3) * 8, &sB[u0 * 8]);
        gload_lds16(B + (size_t)(n0 + (u1 >> 2)) * K + k0 + (u1 & 3) * 8, &sB[u1 * 8]);
        __syncthreads();
        bf16x8 af[4], bfv[4];
#pragma unroll
        for (int i = 0; i < 4; i++) {
            af[i]  = *(const bf16x8*)&sA[(wr * 64 + i * 16 + lr) * 32 + lc * 8];
            bfv[i] = *(const bf16x8*)&sB[(wc * 64 + i * 16 + lr) * 32 + lc * 8];
        }
#pragma unroll
        for (int i = 0; i < 4; i++)
#pragma unroll
            for (int j = 0; j < 4; j++) acc[i][j] = MFMA16(af[i], bfv[j], acc[i][j]);
    }

    if (EPI == 0) {
#pragma unroll
        for (int i = 0; i < 4; i++) {
#pragma unroll
            for (int j = 0; j < 4; j++) {
                const int n = n0 + wc * 64 + j * 16 + lr;
                const int d = n & 63;
#pragma unroll
                for (int r = 0; r < 4; r++) {
                    const int m = m0 + wr * 64 + i * 16 + lc * 4 + r;
                    const int bb = m >> 11, s = m & 2047;
                    const unsigned short val = f2bf(acc[i][j][r]);
                    if (n < 2048) {
                        const int hh = n >> 6;
                        oq[((((size_t)bb * 32 + hh) * 2048 + s) << 6) + d] = val;
                    } else if (n < 2560) {
                        const int hh = (n >> 6) - 32;
                        ok[((((size_t)bb * 8 + hh) * 2048 + s) << 6) + d] = val;
                    } else {
                        const int hh = (n >> 6) - 40;
                        ov[((((size_t)bb * 8 + hh) * 2048 + s) << 6) + d] = val;
                    }
                }
            }
        }
    } else {
#pragma unroll
        for (int i = 0; i < 4; i++)
#pragma unroll
            for (int j = 0; j < 4; j++)
#pragma unroll
                for (int r = 0; r < 4; r++) {
                    const int m = m0 + wr * 64 + i * 16 + lc * 4 + r;
                    const int n = n0 + wc * 64 + j * 16 + lr;
                    of[(size_t)m * N + n] = acc[i][j][r];
                }
    }
}

// ---------------------------------------------------------------- flash attention v5: QBLK=128, 8 waves
// Per-wave structure identical to v4 (verified); staging: K via 1 gload_lds16/thread,
// V via 1 uint4/thread (wave w owns d-chunk 8w); epilogue uses sVt as flat [128][72].
__global__ __launch_bounds__(512) void attn_kernel(
    const unsigned short* __restrict__ Q,
    const unsigned short* __restrict__ K,
    const unsigned short* __restrict__ V,
    const int* __restrict__ dstart,
    unsigned short* __restrict__ AO)
{
    const int qt = 15 - blockIdx.x; // heavy blocks first
    const int h = blockIdx.y, b = blockIdx.z;
    const int kvh = h >> 2;
    const int tid = threadIdx.x, lane = tid & 63, wave = tid >> 6;
    const int lr = lane & 15, lc = lane >> 4;
    const int q0 = qt * 128;
    const int qw = q0 + wave * 16;

    __shared__ __align__(16) unsigned short sK[2][64 * 64];   // chunk-XOR swizzled
    __shared__ __align__(16) unsigned short sVt[2][64][72];   // V^T; flat [128][72] in epilogue

    const unsigned short* Qh = Q + (((size_t)b * 32 + h) * 2048) * 64;
    const unsigned short* Kh = K + (((size_t)b * 8 + kvh) * 2048) * 64;
    const unsigned short* Vh = V + (((size_t)b * 8 + kvh) * 2048) * 64;

    const bf16x8 qf0 = *(const bf16x8*)&Qh[(size_t)(qw + lr) * 64 + lc * 8];
    const bf16x8 qf1 = *(const bf16x8*)&Qh[(size_t)(qw + lr) * 64 + 32 + lc * 8];

    const int qglob = qw + lr;
    const int dsl = dstart[b * 2048 + qglob];
    const int ds_wmin = dstart[b * 2048 + qw];
    const int t0 = dstart[b * 2048 + q0] & ~63;

    const int w8 = wave * 8;
    const int kr = tid >> 3, kc = tid & 7; // 512 threads cover the 64x64 K tile

    auto STAGE_K = [&](int t, int c) {
        gload_lds16(Kh + (size_t)(t + kr) * 64 + ((kc ^ (kr & 7)) * 8), &sK[c][tid * 8]);
    };
    auto WRITE_V = [&](const uint4& va, int c) {
        const unsigned short* pa = (const unsigned short*)&va;
#pragma unroll
        for (int e = 0; e < 8; e++) sVt[c][w8 + e][lane] = pa[e];
    };

    float mrow = -1e30f, lrow = 0.f;
    f32x4 oacc[4];
#pragma unroll
    for (int j = 0; j < 4; j++) oacc[j] = (f32x4){0.f, 0.f, 0.f, 0.f};

    // ---- prologue: stage tile t0 into buf 0
    STAGE_K(t0, 0);
    {
        const uint4 va = *(const uint4*)&Vh[(size_t)(t0 + lane) * 64 + w8];
        asm volatile("s_waitcnt vmcnt(0)" ::: "memory");
        WRITE_V(va, 0);
    }
    __syncthreads();

    int cb = 0;
    for (int t = t0; t < q0 + 128; t += 64, cb ^= 1) {
        const bool more = (t < q0 + 64); // block-uniform
        uint4 va;
        if (more) {
            STAGE_K(t + 64, cb ^ 1);
            va = *(const uint4*)&Vh[(size_t)(t + 64 + lane) * 64 + w8];
        }
        const bool act = !(t > qw + 15 || t + 63 < ds_wmin); // wave-uniform
        union { unsigned int w[4]; bf16x8 v; } B0, B1;

        if (act) {
            // --- QK^T swapped: C[k][q], k = kk*16 + lc*4 + r, q = qw + lr
            f32x4 sc[4];
#pragma unroll
            for (int kk = 0; kk < 4; kk++) {
                const int krow = kk * 16 + lr;
                const bf16x8 kf0 = *(const bf16x8*)&sK[cb][krow * 64 + ((lc ^ (lr & 7)) * 8)];
                const bf16x8 kf1 = *(const bf16x8*)&sK[cb][krow * 64 + (((4 + lc) ^ (lr & 7)) * 8)];
                f32x4 a = (f32x4){0.f, 0.f, 0.f, 0.f};
                a = MFMA16(kf0, qf0, a);
                a = MFMA16(kf1, qf1, a);
                sc[kk] = a;
            }
            // --- mask + scale + in-lane softmax
            float vmax = -3e38f;
#pragma unroll
            for (int kk = 0; kk < 4; kk++)
#pragma unroll
                for (int r = 0; r < 4; r++) {
                    const int kpos = t + kk * 16 + lc * 4 + r;
                    const bool okm = (kpos <= qglob) && (kpos >= dsl);
                    sc[kk][r] = okm ? sc[kk][r] * 0.125f : -3e38f;
                    vmax = fmaxf(vmax, sc[kk][r]);
                }
            vmax = fmaxf(vmax, __shfl_xor(vmax, 16));
            vmax = fmaxf(vmax, __shfl_xor(vmax, 32));
            const float mnew = fmaxf(mrow, vmax);
            const float corr = __expf(mrow - mnew);
            mrow = mnew;

            float rsum = 0.f;
            unsigned int pk[4][2];
#pragma unroll
            for (int kk = 0; kk < 4; kk++) {
                const float p0 = __expf(sc[kk][0] - mnew);
                const float p1 = __expf(sc[kk][1] - mnew);
                const float p2 = __expf(sc[kk][2] - mnew);
                const float p3 = __expf(sc[kk][3] - mnew);
                rsum += (p0 + p1) + (p2 + p3);
                pk[kk][0] = pack_bf2(p0, p1);
                pk[kk][1] = pack_bf2(p2, p3);
            }
            rsum += __shfl_xor(rsum, 16);
            rsum += __shfl_xor(rsum, 32);
            lrow = lrow * corr + rsum;
#pragma unroll
            for (int j = 0; j < 4; j++)
#pragma unroll
                for (int r = 0; r < 4; r++) oacc[j][r] *= corr;

            // --- redistribute P -> PV B-frags (shuffle both kk candidates, select by dest lc>>1)
            const int srcEven = 32 * (lc & 1) + lr;
            const int srcOdd  = srcEven + 16;
            const bool hiKK = (lc & 2) != 0;
            unsigned int a, c;
            a = __shfl(pk[0][0], srcEven); c = __shfl(pk[1][0], srcEven); B0.w[0] = hiKK ? c : a;
            a = __shfl(pk[0][1], srcEven); c = __shfl(pk[1][1], srcEven); B0.w[1] = hiKK ? c : a;
            a = __shfl(pk[0][0], srcOdd);  c = __shfl(pk[1][0], srcOdd);  B0.w[2] = hiKK ? c : a;
            a = __shfl(pk[0][1], srcOdd);  c = __shfl(pk[1][1], srcOdd);  B0.w[3] = hiKK ? c : a;
            a = __shfl(pk[2][0], srcEven); c = __shfl(pk[3][0], srcEven); B1.w[0] = hiKK ? c : a;
            a = __shfl(pk[2][1], srcEven); c = __shfl(pk[3][1], srcEven); B1.w[1] = hiKK ? c : a;
            a = __shfl(pk[2][0], srcOdd);  c = __shfl(pk[3][0], srcOdd);  B1.w[2] = hiKK ? c : a;
            a = __shfl(pk[2][1], srcOdd);  c = __shfl(pk[3][1], srcOdd);  B1.w[3] = hiKK ? c : a;
        }

        if (more) {
            asm volatile("s_waitcnt vmcnt(0)" ::: "memory"); // V(t+64) regs + K(t+64) LDS landed
            WRITE_V(va, cb ^ 1);
        }

        if (act) {
            // --- PV: O^T = V^T x P^T, C[d][q]: d = j*16 + lc*4 + r, q = qw + lr
#pragma unroll
            for (int j = 0; j < 4; j++) {
                const bf16x8 a0 = *(const bf16x8*)&sVt[cb][j * 16 + lr][lc * 8];
                const bf16x8 a1 = *(const bf16x8*)&sVt[cb][j * 16 + lr][32 + lc * 8];
                oacc[j] = MFMA16(a0, B0.v, oacc[j]);
                oacc[j] = MFMA16(a1, B1.v, oacc[j]);
            }
        }
        __syncthreads();
    }

    // --- epilogue: transpose via LDS (sVt viewed as flat [128][72]), coalesced stores
    unsigned short (*E)[72] = (unsigned short (*)[72])&sVt[0][0][0];
    const float inv = 1.0f / lrow;
#pragma unroll
    for (int j = 0; j < 4; j++)
#pragma unroll
        for (int p = 0; p < 2; p++) {
            const unsigned int w = pack_bf2(oacc[j][2 * p] * inv, oacc[j][2 * p + 1] * inv);
            *(unsigned int*)&E[wave * 16 + lr][j * 16 + lc * 4 + 2 * p] = w;
        }
    __syncthreads();
#pragma unroll
    for (int half = 0; half < 2; half++) {
        const int c = lane + 64 * half;
        const int row = c >> 3, ch = c & 7;
        const uint4 o = *(const uint4*)&E[wave * 16 + row][ch * 8];
        *(uint4*)&AO[((size_t)b * 2048 + qw + row) * 2048 + h * 64 + ch * 8] = o;
    }
}

// ---------------------------------------------------------------- host
extern "C" void kernel_launch(void* const* d_in, const int* in_sizes, int n_in,
                              void* d_out, int out_size, void* d_ws, size_t ws_size,
                              hipStream_t stream) {
    const float* x  = (const float*)d_in[0];
    const float* fc = (const float*)d_in[1];
    const int* sid  = (const int*)d_in[2];
    const float* wq = (const float*)d_in[3];
    const float* wk = (const float*)d_in[4];
    const float* wv = (const float*)d_in[5];
    const float* wo = (const float*)d_in[6];
    float* out = (float*)d_out;

    unsigned short* xb   = (unsigned short*)d_ws;
    unsigned short* wqkv = xb + (size_t)4096 * 2048;
    unsigned short* wob  = wqkv + (size_t)3072 * 2048;
    unsigned short* Qb   = wob + (size_t)2048 * 2048;
    unsigned short* Kb   = Qb + (size_t)2 * 32 * 2048 * 64;
    unsigned short* Vb   = Kb + (size_t)2 * 8 * 2048 * 64;
    unsigned short* AO   = Vb + (size_t)2 * 8 * 2048 * 64;
    int* dstart = (int*)(AO + (size_t)4096 * 2048);

    cvt_all_kernel<<<18432, 256, 0, stream>>>(x, wq, wk, wv, wo, xb, wqkv, wob);
    docstart_kernel<<<16, 256, 0, stream>>>(sid, dstart);
    gemm_qkv8<<<dim3(192), 512, 0, stream>>>(xb, wqkv, Qb, Kb, Vb);
    rope_kernel<<<5120, 256, 0, stream>>>(Qb, Kb, fc);
    attn_kernel<<<dim3(16, 32, 2), 512, 0, stream>>>(Qb, Kb, Vb, dstart, AO);
    gemm_bt<1><<<dim3(16, 32), 256, 0, stream>>>(AO, wob, 2048, 2048, nullptr, nullptr, nullptr, out);
}